// Round 10
// baseline (528.362 us; speedup 1.0000x reference)
//
#include <hip/hip_runtime.h>
#include <stdint.h>

// Round 10: R9's conv-fold REVERTED (reg-staging was net-negative: 200->291).
// Back to conv_bf16 + global_load_lds (R8-verified), with new GEMM geometry:
// 256x128 tile, 8 waves in 4x2 grid (wave = 64x64 -> LDS reads -33% vs R8's
// 64x32 waves), half the blocks (epilogue/barrier amortization 2x). 96KB LDS
// dbuf (1 block/CU). T2 swizzle + 2-phase syncthreads pipeline kept verbatim.

typedef __attribute__((ext_vector_type(4))) float f32x4;
typedef __attribute__((ext_vector_type(4))) short s16x4;
typedef __attribute__((ext_vector_type(8))) short s16x8;

#define DEVI static __device__ __forceinline__

DEVI unsigned short f2bf(float f) {
  union { float f; uint32_t u; } v; v.f = f;
  return (unsigned short)((v.u + 0x7FFFu + ((v.u >> 16) & 1u)) >> 16);
}

DEVI f32x4 zero4() { f32x4 z; z[0] = 0.f; z[1] = 0.f; z[2] = 0.f; z[3] = 0.f; return z; }

#if defined(__has_builtin)
#if __has_builtin(__builtin_amdgcn_mfma_f32_16x16x16bf16_1k)
#define MFMA16_BUILTIN 1
#endif
#if __has_builtin(__builtin_amdgcn_global_load_lds)
#define HAS_GLLDS 1
#endif
#endif

DEVI f32x4 mfma16(s16x4 a, s16x4 b, f32x4 c) {
#ifdef MFMA16_BUILTIN
  return __builtin_amdgcn_mfma_f32_16x16x16bf16_1k(a, b, c, 0, 0, 0);
#else
  asm volatile("v_mfma_f32_16x16x16_bf16 %0, %1, %2, %0" : "+v"(c) : "v"(a), "v"(b));
  return c;
#endif
}

DEVI f32x4 mfma32(s16x8 a, s16x8 b, f32x4 c) {
  return __builtin_amdgcn_mfma_f32_16x16x32_bf16(a, b, c, 0, 0, 0);
}

DEVI void stage1k(const unsigned short* g_lane, unsigned short* lds_base) {
#ifdef HAS_GLLDS
  __builtin_amdgcn_global_load_lds(
      (const __attribute__((address_space(1))) unsigned int*)g_lane,
      (__attribute__((address_space(3))) unsigned int*)lds_base, 16, 0, 0);
#else
  *(s16x8*)(lds_base + (threadIdx.x & 63) * 8) = *(const s16x8*)g_lane;
#endif
}

// ---------------- prep kernels ----------------
__global__ void prep_wqkvT(const float* __restrict__ W, unsigned short* __restrict__ WT) {
  int t = blockIdx.x * 256 + threadIdx.x;
  if (t >= 1152 * 384) return;
  int n = t / 384, k = t - n * 384;
  float s = (n < 384) ? 0.17677669529663687f : 1.0f;  // HEAD_DIM^-0.5 folded into Wq
  WT[t] = f2bf(W[(size_t)k * 1152 + n] * s);
}

__global__ void prep_wmT(const float* __restrict__ W, unsigned short* __restrict__ WT) {
  int t = blockIdx.x * 256 + threadIdx.x;
  if (t >= 384 * 384) return;
  int n = t / 384, k = t - n * 384;
  WT[t] = f2bf(W[(size_t)k * 384 + n]);
}

__global__ void prep_bqkv(const float* __restrict__ b, float* __restrict__ bs) {
  int t = blockIdx.x * 256 + threadIdx.x;
  if (t >= 1152) return;
  bs[t] = b[t] * ((t < 384) ? 0.17677669529663687f : 1.0f);
}

// biasF: per-lane fragment order. biasF[((h*16 + jt*4 + it)*64 + lane)*4 + e]
__global__ void prep_biasF(const float* __restrict__ rel, float* __restrict__ biasF) {
  int t = blockIdx.x * 256 + threadIdx.x;  // 12*16*64 = 12288
  if (t >= 12288) return;
  int h = t >> 10;
  int r = (t >> 6) & 15;
  int lane = t & 63;
  int jt = r >> 2, it = r & 3;
  int lg = lane >> 4, lr = lane & 15;
  int i = it * 16 + lr;
#pragma unroll
  for (int e = 0; e < 4; ++e) {
    int j = jt * 16 + lg * 4 + e;
    int idx = ((i >> 3) - (j >> 3) + 7) * 15 + ((i & 7) - (j & 7) + 7);
    biasF[t * 4 + e] = rel[idx * 12 + h];
  }
}

__global__ void fill_val(float* o, int n, float v) {
  int t = blockIdx.x * 256 + threadIdx.x;
  if (t < n) o[t] = v;
}

// ---------------- x fp32 -> bf16 ----------------
__global__ __launch_bounds__(256) void conv_bf16(const float* __restrict__ x,
                                                 unsigned short* __restrict__ xb) {
  const size_t nchunk = 131072UL * 384 / 8;
  const size_t stride = (size_t)gridDim.x * blockDim.x;
  for (size_t i = (size_t)blockIdx.x * blockDim.x + threadIdx.x; i < nchunk; i += stride) {
    f32x4 a = *(const f32x4*)(x + i * 8);
    f32x4 b = *(const f32x4*)(x + i * 8 + 4);
    s16x8 p;
    p[0] = (short)f2bf(a[0]); p[1] = (short)f2bf(a[1]);
    p[2] = (short)f2bf(a[2]); p[3] = (short)f2bf(a[3]);
    p[4] = (short)f2bf(b[0]); p[5] = (short)f2bf(b[1]);
    p[6] = (short)f2bf(b[2]); p[7] = (short)f2bf(b[3]);
    *(s16x8*)(xb + i * 8) = p;
  }
}

// ---------------- GEMM: 256x128 tile, 8 waves 4x2, 2-phase dbuf + T2 swizzle ----
// LDS flat (ushort): buf b at b*24576; A tile [256][64] at +0, B tile [128][64]
// at +16384. Epilogue Q/K tile [256][128] = 64KB uses sm[0..32767].
template <bool QKV_EPI>
__global__ __launch_bounds__(512, 2) void gemm_k(const unsigned short* __restrict__ A,
                                                 const unsigned short* __restrict__ BT,
                                                 const float* __restrict__ bias,
                                                 void* __restrict__ Cv) {
  constexpr int K = 384;
  constexpr int NT = QKV_EPI ? 9 : 3;
  constexpr int N = NT * 128;
  __shared__ unsigned short sm[49152];  // 96 KB
  const int bid = blockIdx.x;
  const int swz = (bid & 7) * (NT * 64) + (bid >> 3);  // nwg = NT*512, bijective
  const int n0 = (swz % NT) * 128;
  const int m0 = (swz / NT) * 256;
  const int tid = threadIdx.x;
  const int lane = tid & 63, wv = tid >> 6;   // wv 0..7
  const int wr = wv >> 1, wc = wv & 1;        // wave grid 4x2: 64 rows x 64 cols
  const int lg = lane >> 4, lr = lane & 15;

  // T2 swizzle write side: lane l covers row l>>3, LDS slot 8*(l&7);
  // its GLOBAL col is 8*((l&7) ^ (l>>3)). LDS dest linear (rule #21).
  const int scol = ((lane & 7) ^ (lane >> 3)) * 8;
  const unsigned short* Ag = A + (size_t)(m0 + wv * 32 + (lane >> 3)) * K + scol;
  const unsigned short* Bg = BT + (size_t)(n0 + wv * 16 + (lane >> 3)) * K + scol;

  f32x4 acc[4][4];
#pragma unroll
  for (int i = 0; i < 4; ++i)
#pragma unroll
    for (int j = 0; j < 4; ++j) acc[i][j] = zero4();

  auto STAGE = [&](int buf, int k0) {
#pragma unroll
    for (int c2 = 0; c2 < 4; ++c2)
      stage1k(Ag + (size_t)(c2 * 8) * K + k0, &sm[buf * 24576 + (wv * 32 + c2 * 8) * 64]);
#pragma unroll
    for (int c2 = 0; c2 < 2; ++c2)
      stage1k(Bg + (size_t)(c2 * 8) * K + k0, &sm[buf * 24576 + 16384 + (wv * 16 + c2 * 8) * 64]);
  };
  // T2 read side: same involution on column bits.
  const int sa = (lr & 7) << 3;
  auto COMPUTE = [&](int buf) {
#pragma unroll
    for (int kk = 0; kk < 64; kk += 32) {
      s16x8 af[4], bf[4];
#pragma unroll
      for (int mt = 0; mt < 4; ++mt)
        af[mt] = *(const s16x8*)&sm[buf * 24576 + (wr * 64 + 16 * mt + lr) * 64 + ((kk + 8 * lg) ^ sa)];
#pragma unroll
      for (int nt = 0; nt < 4; ++nt)
        bf[nt] = *(const s16x8*)&sm[buf * 24576 + 16384 + (wc * 64 + 16 * nt + lr) * 64 + ((kk + 8 * lg) ^ sa)];
#pragma unroll
      for (int mt = 0; mt < 4; ++mt)
#pragma unroll
        for (int nt = 0; nt < 4; ++nt)
          acc[mt][nt] = mfma32(af[mt], bf[nt], acc[mt][nt]);
    }
  };

  // 2-phase pipeline (R7-verified): STAGE(next); COMPUTE(cur); __syncthreads().
  STAGE(0, 0);
  __syncthreads();
  int cur = 0;
#pragma unroll 1
  for (int t = 0; t < 5; ++t) {
    STAGE(cur ^ 1, (t + 1) * 64);
    COMPUTE(cur);
    __syncthreads();
    cur ^= 1;
  }
  COMPUTE(cur);
  __syncthreads();  // epilogue tile overlaps buf1 -> wait for all waves' COMPUTE

  const int crow = m0 + wr * 64 + 4 * lg;
  const int ccol = n0 + wc * 64 + lr;
  if constexpr (QKV_EPI) {
    const int sel = n0 / 384;  // block-uniform
    unsigned short* qkv = (unsigned short*)Cv;
    if (sel < 2) {
      // ---- LDS-staged coalesced epilogue (Q/K), tile [256][128] in sm[0..32767] ----
      unsigned short* tile = &sm[0];
#pragma unroll
      for (int nt = 0; nt < 4; ++nt) {
        const int cc = wc * 64 + 16 * nt + lr;
        const float bv = bias[n0 + cc];
#pragma unroll
        for (int mt = 0; mt < 4; ++mt) {
#pragma unroll
          for (int e = 0; e < 4; ++e) {
            const int r = wr * 64 + 16 * mt + 4 * lg + e;
            tile[r * 128 + (cc ^ ((r & 7) << 3))] = f2bf(acc[mt][nt][e] + bv);
          }
        }
      }
      __syncthreads();
      // readback: 2 lanes per row (tr), each lane 8 of 16 16B-chunks;
      // chunk c: head = c>>2, 16B quarter = c&3.
      const int hbase = (n0 - sel * 384) >> 5;
      const int tr = wv * 32 + (lane >> 1);
      const int gtok = m0 + tr;
      const int w2 = gtok >> 6, t0r = gtok & 63;
#pragma unroll
      for (int cc2 = 0; cc2 < 8; ++cc2) {
        const int c = cc2 * 2 + (lane & 1);
        s16x8 v = *(const s16x8*)&tile[tr * 128 + ((c * 8) ^ ((tr & 7) << 3))];
        unsigned short* dst = qkv + (((size_t)w2 * 12 + hbase + (c >> 2)) * 3 + sel) * 2048 +
                              t0r * 32 + (c & 3) * 8;
        *(s16x8*)dst = v;
      }
    } else {
      // ---- V: direct transposed store (s16x4 = 4 consecutive tokens) ----
      const int window = crow >> 6;   // wave-uniform (wr*64 block)
      const int t0 = crow & 63;       // 4*lg
#pragma unroll
      for (int nt = 0; nt < 4; ++nt) {
        const int col = ccol + 16 * nt;
        const int hcol = col - 768;
        const int h = hcol >> 5, d = hcol & 31;
        const float bv = bias[col];
        unsigned short* base = qkv + (((size_t)window * 12 + h) * 3 + 2) * 2048;
#pragma unroll
        for (int mt = 0; mt < 4; ++mt) {
          s16x4 pk;
#pragma unroll
          for (int e = 0; e < 4; ++e) pk[e] = (short)f2bf(acc[mt][nt][e] + bv);
          *(s16x4*)&base[d * 64 + t0 + 16 * mt] = pk;
        }
      }
    }
  } else {
    float* C = (float*)Cv;
#pragma unroll
    for (int mt = 0; mt < 4; ++mt)
#pragma unroll
      for (int nt = 0; nt < 4; ++nt) {
        const int col = ccol + 16 * nt;
        const float bv = bias[col];
#pragma unroll
        for (int e = 0; e < 4; ++e)
          C[(size_t)(crow + 16 * mt + e) * N + col] = acc[mt][nt][e] + bv;
      }
  }
}

// ---------------- attention: one wave per (window, head), no LDS ----------------
__global__ __launch_bounds__(256) void attn_k(const unsigned short* __restrict__ qkv,
                                              const float* __restrict__ biasF,
                                              unsigned short* __restrict__ attnout) {
  const int lane = threadIdx.x & 63;
  const int wv = threadIdx.x >> 6;
  const int wh = blockIdx.x * 4 + wv;  // [0, 24576)
  const int window = wh / 12;
  const int h = wh - window * 12;
  const int lg = lane >> 4, lr = lane & 15;

  const unsigned short* hb = qkv + (size_t)wh * 6144;
  const unsigned short* Qh = hb;
  const unsigned short* Kh = hb + 2048;
  const unsigned short* Vth = hb + 4096;

  s16x8 ka[4], qb[4];
#pragma unroll
  for (int jt = 0; jt < 4; ++jt)
    ka[jt] = *(const s16x8*)&Kh[(jt * 16 + lr) * 32 + 8 * lg];
#pragma unroll
  for (int it = 0; it < 4; ++it)
    qb[it] = *(const s16x8*)&Qh[(it * 16 + lr) * 32 + 8 * lg];

  f32x4 c[4][4];
#pragma unroll
  for (int a = 0; a < 4; ++a)
#pragma unroll
    for (int b2 = 0; b2 < 4; ++b2) c[a][b2] = zero4();

#pragma unroll
  for (int jt = 0; jt < 4; ++jt)
#pragma unroll
    for (int it = 0; it < 4; ++it)
      c[jt][it] = mfma32(ka[jt], qb[it], c[jt][it]);

  const f32x4* bF = (const f32x4*)biasF + ((size_t)h * 16) * 64 + lane;
#pragma unroll
  for (int jt = 0; jt < 4; ++jt)
#pragma unroll
    for (int it = 0; it < 4; ++it)
      c[jt][it] += bF[(jt * 4 + it) * 64];

  s16x4 pb[4][4];
#pragma unroll
  for (int it = 0; it < 4; ++it) {
    float m = -3.0e38f;
#pragma unroll
    for (int jt = 0; jt < 4; ++jt)
#pragma unroll
      for (int e = 0; e < 4; ++e) m = fmaxf(m, c[jt][it][e]);
    m = fmaxf(m, __shfl_xor(m, 16));
    m = fmaxf(m, __shfl_xor(m, 32));
    float s = 0.f;
#pragma unroll
    for (int jt = 0; jt < 4; ++jt)
#pragma unroll
      for (int e = 0; e < 4; ++e) {
        float p = __expf(c[jt][it][e] - m);
        c[jt][it][e] = p;
        s += p;
      }
    s += __shfl_xor(s, 16);
    s += __shfl_xor(s, 32);
    const float inv = 1.f / s;
#pragma unroll
    for (int jt = 0; jt < 4; ++jt) {
      s16x4 pk;
#pragma unroll
      for (int e = 0; e < 4; ++e) pk[e] = (short)f2bf(c[jt][it][e] * inv);
      pb[jt][it] = pk;
    }
  }

  f32x4 o[2][4];
#pragma unroll
  for (int a = 0; a < 2; ++a)
#pragma unroll
    for (int b2 = 0; b2 < 4; ++b2) o[a][b2] = zero4();

#pragma unroll
  for (int jt = 0; jt < 4; ++jt) {
    s16x4 va[2];
#pragma unroll
    for (int dt = 0; dt < 2; ++dt)
      va[dt] = *(const s16x4*)&Vth[(dt * 16 + lr) * 64 + jt * 16 + 4 * lg];
#pragma unroll
    for (int dt = 0; dt < 2; ++dt)
#pragma unroll
      for (int it = 0; it < 4; ++it)
        o[dt][it] = mfma16(va[dt], pb[jt][it], o[dt][it]);
  }

  unsigned short* ob = attnout + (size_t)window * 64 * 384;
#pragma unroll
  for (int dt = 0; dt < 2; ++dt)
#pragma unroll
    for (int it = 0; it < 4; ++it) {
      s16x4 pk;
#pragma unroll
      for (int e = 0; e < 4; ++e) pk[e] = (short)f2bf(o[dt][it][e]);
      *(s16x4*)&ob[(size_t)(it * 16 + lr) * 384 + h * 32 + dt * 16 + 4 * lg] = pk;
    }
}

extern "C" void kernel_launch(void* const* d_in, const int* in_sizes, int n_in,
                              void* d_out, int out_size, void* d_ws, size_t ws_size,
                              hipStream_t stream) {
  const float* x = (const float*)d_in[0];
  const float* Wqkv = (const float*)d_in[1];
  const float* bqkv = (const float*)d_in[2];
  const float* Wm = (const float*)d_in[3];
  const float* bm = (const float*)d_in[4];
  const float* rel = (const float*)d_in[5];

  const size_t M = 131072;  // B*G*P
  char* ws = (char*)d_ws;
  size_t off = 0;
  unsigned short* qkv = (unsigned short*)(ws + off);   off += M * 1152 * 2;  // 302 MB
  unsigned short* xb = (unsigned short*)(ws + off);    off += M * 384 * 2;   // 100 MB (reused as attnout)
  unsigned short* WqkvT = (unsigned short*)(ws + off); off += 1152 * 384 * 2;
  unsigned short* WmT = (unsigned short*)(ws + off);   off += 384 * 384 * 2;
  float* biasF = (float*)(ws + off);                   off += 12 * 16 * 64 * 4 * 4;
  float* bqkvs = (float*)(ws + off);                   off += 1152 * 4;
  unsigned short* attnout = xb;  // xb is dead after gemm1

  if (ws_size < off) {
    fill_val<<<(out_size + 255) / 256, 256, 0, stream>>>((float*)d_out, out_size, 12345.0f);
    return;
  }

  prep_wqkvT<<<(1152 * 384 + 255) / 256, 256, 0, stream>>>(Wqkv, WqkvT);
  prep_wmT<<<(384 * 384 + 255) / 256, 256, 0, stream>>>(Wm, WmT);
  prep_bqkv<<<5, 256, 0, stream>>>(bqkv, bqkvs);
  prep_biasF<<<48, 256, 0, stream>>>(rel, biasF);
  conv_bf16<<<2048, 256, 0, stream>>>(x, xb);

  gemm_k<true><<<4608, 512, 0, stream>>>(xb, WqkvT, bqkvs, qkv);
  attn_k<<<6144, 256, 0, stream>>>(qkv, biasF, attnout);
  gemm_k<false><<<1536, 512, 0, stream>>>(attnout, WmT, bm, d_out);
}

// Round 11
// 469.142 us; speedup vs baseline: 1.1262x; 1.1262x over previous
//
#include <hip/hip_runtime.h>
#include <stdint.h>

// Round 11: REVERT to R8 (best verified, 462 us) — R9 reg-staging and R10
// 256x128/96KB geometry both regressed (1 block/CU loses inter-block barrier
// overlap). New: attn_k gets (a) V-prefetch (issue all va loads with ka/qb,
// before QK/softmax — hides L2 latency under compute), (b) T5 setprio(1)
// around MFMA clusters (attn is m191's positive regime: independent waves,
// no barriers). GEMMs/conv/prep byte-identical to R8.

typedef __attribute__((ext_vector_type(4))) float f32x4;
typedef __attribute__((ext_vector_type(4))) short s16x4;
typedef __attribute__((ext_vector_type(8))) short s16x8;

#define DEVI static __device__ __forceinline__

DEVI unsigned short f2bf(float f) {
  union { float f; uint32_t u; } v; v.f = f;
  return (unsigned short)((v.u + 0x7FFFu + ((v.u >> 16) & 1u)) >> 16);
}

DEVI f32x4 zero4() { f32x4 z; z[0] = 0.f; z[1] = 0.f; z[2] = 0.f; z[3] = 0.f; return z; }

#if defined(__has_builtin)
#if __has_builtin(__builtin_amdgcn_mfma_f32_16x16x16bf16_1k)
#define MFMA16_BUILTIN 1
#endif
#if __has_builtin(__builtin_amdgcn_global_load_lds)
#define HAS_GLLDS 1
#endif
#endif

DEVI f32x4 mfma16(s16x4 a, s16x4 b, f32x4 c) {
#ifdef MFMA16_BUILTIN
  return __builtin_amdgcn_mfma_f32_16x16x16bf16_1k(a, b, c, 0, 0, 0);
#else
  asm volatile("v_mfma_f32_16x16x16_bf16 %0, %1, %2, %0" : "+v"(c) : "v"(a), "v"(b));
  return c;
#endif
}

DEVI f32x4 mfma32(s16x8 a, s16x8 b, f32x4 c) {
  return __builtin_amdgcn_mfma_f32_16x16x32_bf16(a, b, c, 0, 0, 0);
}

DEVI void stage1k(const unsigned short* g_lane, unsigned short* lds_base) {
#ifdef HAS_GLLDS
  __builtin_amdgcn_global_load_lds(
      (const __attribute__((address_space(1))) unsigned int*)g_lane,
      (__attribute__((address_space(3))) unsigned int*)lds_base, 16, 0, 0);
#else
  *(s16x8*)(lds_base + (threadIdx.x & 63) * 8) = *(const s16x8*)g_lane;
#endif
}

// ---------------- prep kernels ----------------
__global__ void prep_wqkvT(const float* __restrict__ W, unsigned short* __restrict__ WT) {
  int t = blockIdx.x * 256 + threadIdx.x;
  if (t >= 1152 * 384) return;
  int n = t / 384, k = t - n * 384;
  float s = (n < 384) ? 0.17677669529663687f : 1.0f;  // HEAD_DIM^-0.5 folded into Wq
  WT[t] = f2bf(W[(size_t)k * 1152 + n] * s);
}

__global__ void prep_wmT(const float* __restrict__ W, unsigned short* __restrict__ WT) {
  int t = blockIdx.x * 256 + threadIdx.x;
  if (t >= 384 * 384) return;
  int n = t / 384, k = t - n * 384;
  WT[t] = f2bf(W[(size_t)k * 384 + n]);
}

__global__ void prep_bqkv(const float* __restrict__ b, float* __restrict__ bs) {
  int t = blockIdx.x * 256 + threadIdx.x;
  if (t >= 1152) return;
  bs[t] = b[t] * ((t < 384) ? 0.17677669529663687f : 1.0f);
}

// biasF: per-lane fragment order. biasF[((h*16 + jt*4 + it)*64 + lane)*4 + e]
__global__ void prep_biasF(const float* __restrict__ rel, float* __restrict__ biasF) {
  int t = blockIdx.x * 256 + threadIdx.x;  // 12*16*64 = 12288
  if (t >= 12288) return;
  int h = t >> 10;
  int r = (t >> 6) & 15;
  int lane = t & 63;
  int jt = r >> 2, it = r & 3;
  int lg = lane >> 4, lr = lane & 15;
  int i = it * 16 + lr;
#pragma unroll
  for (int e = 0; e < 4; ++e) {
    int j = jt * 16 + lg * 4 + e;
    int idx = ((i >> 3) - (j >> 3) + 7) * 15 + ((i & 7) - (j & 7) + 7);
    biasF[t * 4 + e] = rel[idx * 12 + h];
  }
}

__global__ void fill_val(float* o, int n, float v) {
  int t = blockIdx.x * 256 + threadIdx.x;
  if (t < n) o[t] = v;
}

// ---------------- x fp32 -> bf16 ----------------
__global__ __launch_bounds__(256) void conv_bf16(const float* __restrict__ x,
                                                 unsigned short* __restrict__ xb) {
  const size_t nchunk = 131072UL * 384 / 8;
  const size_t stride = (size_t)gridDim.x * blockDim.x;
  for (size_t i = (size_t)blockIdx.x * blockDim.x + threadIdx.x; i < nchunk; i += stride) {
    f32x4 a = *(const f32x4*)(x + i * 8);
    f32x4 b = *(const f32x4*)(x + i * 8 + 4);
    s16x8 p;
    p[0] = (short)f2bf(a[0]); p[1] = (short)f2bf(a[1]);
    p[2] = (short)f2bf(a[2]); p[3] = (short)f2bf(a[3]);
    p[4] = (short)f2bf(b[0]); p[5] = (short)f2bf(b[1]);
    p[6] = (short)f2bf(b[2]); p[7] = (short)f2bf(b[3]);
    *(s16x8*)(xb + i * 8) = p;
  }
}

// ---------------- GEMM (8 waves, 2-phase dbuf + T2 swizzle) — R8 verbatim ----------
template <bool QKV_EPI>
__global__ __launch_bounds__(512, 4) void gemm_k(const unsigned short* __restrict__ A,
                                                 const unsigned short* __restrict__ BT,
                                                 const float* __restrict__ bias,
                                                 void* __restrict__ Cv) {
  constexpr int K = 384;
  constexpr int NT = QKV_EPI ? 9 : 3;
  constexpr int N = NT * 128;
  __shared__ unsigned short sm[2][16384];
  const int bid = blockIdx.x;
  const int swz = (bid & 7) * (NT * 128) + (bid >> 3);  // XCD-aware, bijective
  const int n0 = (swz % NT) * 128;
  const int m0 = (swz / NT) * 128;
  const int tid = threadIdx.x;
  const int lane = tid & 63, wv = tid >> 6;       // wv 0..7
  const int wr = wv >> 2, wc = wv & 3;            // wave grid 2x4: 64 rows x 32 cols
  const int lg = lane >> 4, lr = lane & 15;

  const int scol = ((lane & 7) ^ (lane >> 3)) * 8;
  const unsigned short* Ag = A + (size_t)(m0 + wv * 16 + (lane >> 3)) * K + scol;
  const unsigned short* Bg = BT + (size_t)(n0 + wv * 16 + (lane >> 3)) * K + scol;

  f32x4 acc[4][2];
#pragma unroll
  for (int i = 0; i < 4; ++i)
#pragma unroll
    for (int j = 0; j < 2; ++j) acc[i][j] = zero4();

  auto STAGE = [&](int buf, int k0) {
#pragma unroll
    for (int c2 = 0; c2 < 2; ++c2)
      stage1k(Ag + (size_t)(c2 * 8) * K + k0, &sm[buf][(wv * 16 + c2 * 8) * 64]);
#pragma unroll
    for (int c2 = 0; c2 < 2; ++c2)
      stage1k(Bg + (size_t)(c2 * 8) * K + k0, &sm[buf][8192 + (wv * 16 + c2 * 8) * 64]);
  };
  const int sa = (lr & 7) << 3;
  auto COMPUTE = [&](int buf) {
#pragma unroll
    for (int kk = 0; kk < 64; kk += 32) {
      s16x8 af[4], bf[2];
#pragma unroll
      for (int mt = 0; mt < 4; ++mt)
        af[mt] = *(const s16x8*)&sm[buf][(wr * 64 + 16 * mt + lr) * 64 + ((kk + 8 * lg) ^ sa)];
#pragma unroll
      for (int nt = 0; nt < 2; ++nt)
        bf[nt] = *(const s16x8*)&sm[buf][8192 + (wc * 32 + 16 * nt + lr) * 64 + ((kk + 8 * lg) ^ sa)];
#pragma unroll
      for (int mt = 0; mt < 4; ++mt)
#pragma unroll
        for (int nt = 0; nt < 2; ++nt)
          acc[mt][nt] = mfma32(af[mt], bf[nt], acc[mt][nt]);
    }
  };

  STAGE(0, 0);
  __syncthreads();
  int cur = 0;
#pragma unroll 1
  for (int t = 0; t < 5; ++t) {
    STAGE(cur ^ 1, (t + 1) * 64);
    COMPUTE(cur);
    __syncthreads();
    cur ^= 1;
  }
  COMPUTE(cur);  // cur == 1: final compute reads sm[1]; epilogue tile uses sm[0]

  const int crow = m0 + wr * 64 + 4 * lg;
  const int ccol = n0 + wc * 32 + lr;
  if constexpr (QKV_EPI) {
    const int sel = n0 / 384;  // block-uniform
    unsigned short* qkv = (unsigned short*)Cv;
    if (sel < 2) {
      unsigned short* tile = &sm[0][0];
#pragma unroll
      for (int nt = 0; nt < 2; ++nt) {
        const int cc = wc * 32 + 16 * nt + lr;
        const float bv = bias[n0 + cc];
#pragma unroll
        for (int mt = 0; mt < 4; ++mt) {
#pragma unroll
          for (int e = 0; e < 4; ++e) {
            const int r = wr * 64 + 16 * mt + 4 * lg + e;
            tile[r * 128 + (cc ^ ((r & 7) << 3))] = f2bf(acc[mt][nt][e] + bv);
          }
        }
      }
      __syncthreads();
      const int hbase = (n0 - sel * 384) >> 5;
      const int tr = wv * 16 + (lane >> 2);
      const int gtok = m0 + tr;
      const int w2 = gtok >> 6, t0r = gtok & 63;
#pragma unroll
      for (int hh = 0; hh < 4; ++hh) {
        const int chunk = hh * 4 + (lane & 3);
        s16x8 v = *(const s16x8*)&tile[tr * 128 + ((chunk * 8) ^ ((tr & 7) << 3))];
        unsigned short* dst = qkv + (((size_t)w2 * 12 + hbase + hh) * 3 + sel) * 2048 +
                              t0r * 32 + (lane & 3) * 8;
        *(s16x8*)dst = v;
      }
    } else {
      const int window = crow >> 6;
      const int t0 = crow & 63;
#pragma unroll
      for (int nt = 0; nt < 2; ++nt) {
        const int col = ccol + 16 * nt;
        const int hcol = col - 768;
        const int h = hcol >> 5, d = hcol & 31;
        const float bv = bias[col];
        unsigned short* base = qkv + (((size_t)window * 12 + h) * 3 + 2) * 2048;
#pragma unroll
        for (int mt = 0; mt < 4; ++mt) {
          s16x4 pk;
#pragma unroll
          for (int e = 0; e < 4; ++e) pk[e] = (short)f2bf(acc[mt][nt][e] + bv);
          *(s16x4*)&base[d * 64 + t0 + 16 * mt] = pk;
        }
      }
    }
  } else {
    float* C = (float*)Cv;
#pragma unroll
    for (int mt = 0; mt < 4; ++mt)
#pragma unroll
      for (int nt = 0; nt < 2; ++nt) {
        const int col = ccol + 16 * nt;
        const float bv = bias[col];
#pragma unroll
        for (int e = 0; e < 4; ++e)
          C[(size_t)(crow + 16 * mt + e) * N + col] = acc[mt][nt][e] + bv;
      }
  }
}

// ---------------- attention: one wave per (window, head), no LDS ----------------
// R11: all global loads (K, Q, V) issued up front; setprio around MFMA clusters.
__global__ __launch_bounds__(256) void attn_k(const unsigned short* __restrict__ qkv,
                                              const float* __restrict__ biasF,
                                              unsigned short* __restrict__ attnout) {
  const int lane = threadIdx.x & 63;
  const int wv = threadIdx.x >> 6;
  const int wh = blockIdx.x * 4 + wv;  // [0, 24576)
  const int window = wh / 12;
  const int h = wh - window * 12;
  const int lg = lane >> 4, lr = lane & 15;

  const unsigned short* hb = qkv + (size_t)wh * 6144;
  const unsigned short* Qh = hb;
  const unsigned short* Kh = hb + 2048;
  const unsigned short* Vth = hb + 4096;

  // issue ALL global loads first: K/Q frags + V frags (V latency hides under
  // QK MFMA + softmax VALU)
  s16x8 ka[4], qb[4];
#pragma unroll
  for (int jt = 0; jt < 4; ++jt)
    ka[jt] = *(const s16x8*)&Kh[(jt * 16 + lr) * 32 + 8 * lg];
#pragma unroll
  for (int it = 0; it < 4; ++it)
    qb[it] = *(const s16x8*)&Qh[(it * 16 + lr) * 32 + 8 * lg];

  s16x4 va[4][2];
#pragma unroll
  for (int jt = 0; jt < 4; ++jt)
#pragma unroll
    for (int dt = 0; dt < 2; ++dt)
      va[jt][dt] = *(const s16x4*)&Vth[(dt * 16 + lr) * 64 + jt * 16 + 4 * lg];

  f32x4 c[4][4];
#pragma unroll
  for (int a = 0; a < 4; ++a)
#pragma unroll
    for (int b2 = 0; b2 < 4; ++b2) c[a][b2] = zero4();

  __builtin_amdgcn_s_setprio(1);
#pragma unroll
  for (int jt = 0; jt < 4; ++jt)
#pragma unroll
    for (int it = 0; it < 4; ++it)
      c[jt][it] = mfma32(ka[jt], qb[it], c[jt][it]);
  __builtin_amdgcn_s_setprio(0);

  const f32x4* bF = (const f32x4*)biasF + ((size_t)h * 16) * 64 + lane;
#pragma unroll
  for (int jt = 0; jt < 4; ++jt)
#pragma unroll
    for (int it = 0; it < 4; ++it)
      c[jt][it] += bF[(jt * 4 + it) * 64];

  s16x4 pb[4][4];
#pragma unroll
  for (int it = 0; it < 4; ++it) {
    float m = -3.0e38f;
#pragma unroll
    for (int jt = 0; jt < 4; ++jt)
#pragma unroll
      for (int e = 0; e < 4; ++e) m = fmaxf(m, c[jt][it][e]);
    m = fmaxf(m, __shfl_xor(m, 16));
    m = fmaxf(m, __shfl_xor(m, 32));
    float s = 0.f;
#pragma unroll
    for (int jt = 0; jt < 4; ++jt)
#pragma unroll
      for (int e = 0; e < 4; ++e) {
        float p = __expf(c[jt][it][e] - m);
        c[jt][it][e] = p;
        s += p;
      }
    s += __shfl_xor(s, 16);
    s += __shfl_xor(s, 32);
    const float inv = 1.f / s;
#pragma unroll
    for (int jt = 0; jt < 4; ++jt) {
      s16x4 pk;
#pragma unroll
      for (int e = 0; e < 4; ++e) pk[e] = (short)f2bf(c[jt][it][e] * inv);
      pb[jt][it] = pk;
    }
  }

  f32x4 o[2][4];
#pragma unroll
  for (int a = 0; a < 2; ++a)
#pragma unroll
    for (int b2 = 0; b2 < 4; ++b2) o[a][b2] = zero4();

  __builtin_amdgcn_s_setprio(1);
#pragma unroll
  for (int jt = 0; jt < 4; ++jt)
#pragma unroll
    for (int dt = 0; dt < 2; ++dt)
#pragma unroll
      for (int it = 0; it < 4; ++it)
        o[dt][it] = mfma16(va[jt][dt], pb[jt][it], o[dt][it]);
  __builtin_amdgcn_s_setprio(0);

  unsigned short* ob = attnout + (size_t)window * 64 * 384;
#pragma unroll
  for (int dt = 0; dt < 2; ++dt)
#pragma unroll
    for (int it = 0; it < 4; ++it) {
      s16x4 pk;
#pragma unroll
      for (int e = 0; e < 4; ++e) pk[e] = (short)f2bf(o[dt][it][e]);
      *(s16x4*)&ob[(size_t)(it * 16 + lr) * 384 + h * 32 + dt * 16 + 4 * lg] = pk;
    }
}

extern "C" void kernel_launch(void* const* d_in, const int* in_sizes, int n_in,
                              void* d_out, int out_size, void* d_ws, size_t ws_size,
                              hipStream_t stream) {
  const float* x = (const float*)d_in[0];
  const float* Wqkv = (const float*)d_in[1];
  const float* bqkv = (const float*)d_in[2];
  const float* Wm = (const float*)d_in[3];
  const float* bm = (const float*)d_in[4];
  const float* rel = (const float*)d_in[5];

  const size_t M = 131072;  // B*G*P
  char* ws = (char*)d_ws;
  size_t off = 0;
  unsigned short* qkv = (unsigned short*)(ws + off);   off += M * 1152 * 2;  // 302 MB
  unsigned short* xb = (unsigned short*)(ws + off);    off += M * 384 * 2;   // 100 MB (reused as attnout)
  unsigned short* WqkvT = (unsigned short*)(ws + off); off += 1152 * 384 * 2;
  unsigned short* WmT = (unsigned short*)(ws + off);   off += 384 * 384 * 2;
  float* biasF = (float*)(ws + off);                   off += 12 * 16 * 64 * 4 * 4;
  float* bqkvs = (float*)(ws + off);                   off += 1152 * 4;
  unsigned short* attnout = xb;  // xb is dead after gemm1

  if (ws_size < off) {
    fill_val<<<(out_size + 255) / 256, 256, 0, stream>>>((float*)d_out, out_size, 12345.0f);
    return;
  }

  prep_wqkvT<<<(1152 * 384 + 255) / 256, 256, 0, stream>>>(Wqkv, WqkvT);
  prep_wmT<<<(384 * 384 + 255) / 256, 256, 0, stream>>>(Wm, WmT);
  prep_bqkv<<<5, 256, 0, stream>>>(bqkv, bqkvs);
  prep_biasF<<<48, 256, 0, stream>>>(rel, biasF);
  conv_bf16<<<2048, 256, 0, stream>>>(x, xb);

  gemm_k<true><<<9216, 512, 0, stream>>>(xb, WqkvT, bqkvs, qkv);
  attn_k<<<6144, 256, 0, stream>>>(qkv, biasF, attnout);
  gemm_k<false><<<3072, 512, 0, stream>>>(attnout, WmT, bm, d_out);
}

// Round 12
// 459.203 us; speedup vs baseline: 1.1506x; 1.0216x over previous
//
#include <hip/hip_runtime.h>
#include <stdint.h>

// Round 12: R8 base (best verified, 462us; attn fully reverted to R8 form).
// GEMM loop upgraded to counted-vmcnt with a CLEAN invariant (unlike R6):
//   STAGE_t (4 loads); vmcnt(4) [= only STAGE_t may stay in flight -> STAGE_{t-1}
//   retired]; s_barrier; COMPUTE(cur); s_barrier.
// Loads span the whole COMPUTE phase instead of draining at the barrier.
// sched_barrier(0) fences pin ordering (rule #18); memory clobbers keep
// gload_lds from crossing the waitcnt.

typedef __attribute__((ext_vector_type(4))) float f32x4;
typedef __attribute__((ext_vector_type(4))) short s16x4;
typedef __attribute__((ext_vector_type(8))) short s16x8;

#define DEVI static __device__ __forceinline__

DEVI unsigned short f2bf(float f) {
  union { float f; uint32_t u; } v; v.f = f;
  return (unsigned short)((v.u + 0x7FFFu + ((v.u >> 16) & 1u)) >> 16);
}

DEVI f32x4 zero4() { f32x4 z; z[0] = 0.f; z[1] = 0.f; z[2] = 0.f; z[3] = 0.f; return z; }

#if defined(__has_builtin)
#if __has_builtin(__builtin_amdgcn_mfma_f32_16x16x16bf16_1k)
#define MFMA16_BUILTIN 1
#endif
#if __has_builtin(__builtin_amdgcn_global_load_lds)
#define HAS_GLLDS 1
#endif
#endif

DEVI f32x4 mfma16(s16x4 a, s16x4 b, f32x4 c) {
#ifdef MFMA16_BUILTIN
  return __builtin_amdgcn_mfma_f32_16x16x16bf16_1k(a, b, c, 0, 0, 0);
#else
  asm volatile("v_mfma_f32_16x16x16_bf16 %0, %1, %2, %0" : "+v"(c) : "v"(a), "v"(b));
  return c;
#endif
}

DEVI f32x4 mfma32(s16x8 a, s16x8 b, f32x4 c) {
  return __builtin_amdgcn_mfma_f32_16x16x32_bf16(a, b, c, 0, 0, 0);
}

DEVI void stage1k(const unsigned short* g_lane, unsigned short* lds_base) {
#ifdef HAS_GLLDS
  __builtin_amdgcn_global_load_lds(
      (const __attribute__((address_space(1))) unsigned int*)g_lane,
      (__attribute__((address_space(3))) unsigned int*)lds_base, 16, 0, 0);
#else
  *(s16x8*)(lds_base + (threadIdx.x & 63) * 8) = *(const s16x8*)g_lane;
#endif
}

// ---------------- prep kernels ----------------
__global__ void prep_wqkvT(const float* __restrict__ W, unsigned short* __restrict__ WT) {
  int t = blockIdx.x * 256 + threadIdx.x;
  if (t >= 1152 * 384) return;
  int n = t / 384, k = t - n * 384;
  float s = (n < 384) ? 0.17677669529663687f : 1.0f;  // HEAD_DIM^-0.5 folded into Wq
  WT[t] = f2bf(W[(size_t)k * 1152 + n] * s);
}

__global__ void prep_wmT(const float* __restrict__ W, unsigned short* __restrict__ WT) {
  int t = blockIdx.x * 256 + threadIdx.x;
  if (t >= 384 * 384) return;
  int n = t / 384, k = t - n * 384;
  WT[t] = f2bf(W[(size_t)k * 384 + n]);
}

__global__ void prep_bqkv(const float* __restrict__ b, float* __restrict__ bs) {
  int t = blockIdx.x * 256 + threadIdx.x;
  if (t >= 1152) return;
  bs[t] = b[t] * ((t < 384) ? 0.17677669529663687f : 1.0f);
}

// biasF: per-lane fragment order. biasF[((h*16 + jt*4 + it)*64 + lane)*4 + e]
__global__ void prep_biasF(const float* __restrict__ rel, float* __restrict__ biasF) {
  int t = blockIdx.x * 256 + threadIdx.x;  // 12*16*64 = 12288
  if (t >= 12288) return;
  int h = t >> 10;
  int r = (t >> 6) & 15;
  int lane = t & 63;
  int jt = r >> 2, it = r & 3;
  int lg = lane >> 4, lr = lane & 15;
  int i = it * 16 + lr;
#pragma unroll
  for (int e = 0; e < 4; ++e) {
    int j = jt * 16 + lg * 4 + e;
    int idx = ((i >> 3) - (j >> 3) + 7) * 15 + ((i & 7) - (j & 7) + 7);
    biasF[t * 4 + e] = rel[idx * 12 + h];
  }
}

__global__ void fill_val(float* o, int n, float v) {
  int t = blockIdx.x * 256 + threadIdx.x;
  if (t < n) o[t] = v;
}

// ---------------- x fp32 -> bf16 ----------------
__global__ __launch_bounds__(256) void conv_bf16(const float* __restrict__ x,
                                                 unsigned short* __restrict__ xb) {
  const size_t nchunk = 131072UL * 384 / 8;
  const size_t stride = (size_t)gridDim.x * blockDim.x;
  for (size_t i = (size_t)blockIdx.x * blockDim.x + threadIdx.x; i < nchunk; i += stride) {
    f32x4 a = *(const f32x4*)(x + i * 8);
    f32x4 b = *(const f32x4*)(x + i * 8 + 4);
    s16x8 p;
    p[0] = (short)f2bf(a[0]); p[1] = (short)f2bf(a[1]);
    p[2] = (short)f2bf(a[2]); p[3] = (short)f2bf(a[3]);
    p[4] = (short)f2bf(b[0]); p[5] = (short)f2bf(b[1]);
    p[6] = (short)f2bf(b[2]); p[7] = (short)f2bf(b[3]);
    *(s16x8*)(xb + i * 8) = p;
  }
}

// ---------------- GEMM (8 waves, counted-vmcnt dbuf + T2 swizzle) ----------------
template <bool QKV_EPI>
__global__ __launch_bounds__(512, 4) void gemm_k(const unsigned short* __restrict__ A,
                                                 const unsigned short* __restrict__ BT,
                                                 const float* __restrict__ bias,
                                                 void* __restrict__ Cv) {
  constexpr int K = 384;
  constexpr int NT = QKV_EPI ? 9 : 3;
  constexpr int N = NT * 128;
  __shared__ unsigned short sm[2][16384];
  const int bid = blockIdx.x;
  const int swz = (bid & 7) * (NT * 128) + (bid >> 3);  // XCD-aware, bijective
  const int n0 = (swz % NT) * 128;
  const int m0 = (swz / NT) * 128;
  const int tid = threadIdx.x;
  const int lane = tid & 63, wv = tid >> 6;       // wv 0..7
  const int wr = wv >> 2, wc = wv & 3;            // wave grid 2x4: 64 rows x 32 cols
  const int lg = lane >> 4, lr = lane & 15;

  const int scol = ((lane & 7) ^ (lane >> 3)) * 8;
  const unsigned short* Ag = A + (size_t)(m0 + wv * 16 + (lane >> 3)) * K + scol;
  const unsigned short* Bg = BT + (size_t)(n0 + wv * 16 + (lane >> 3)) * K + scol;

  f32x4 acc[4][2];
#pragma unroll
  for (int i = 0; i < 4; ++i)
#pragma unroll
    for (int j = 0; j < 2; ++j) acc[i][j] = zero4();

  auto STAGE = [&](int buf, int k0) {  // 4 gload_lds per thread
#pragma unroll
    for (int c2 = 0; c2 < 2; ++c2)
      stage1k(Ag + (size_t)(c2 * 8) * K + k0, &sm[buf][(wv * 16 + c2 * 8) * 64]);
#pragma unroll
    for (int c2 = 0; c2 < 2; ++c2)
      stage1k(Bg + (size_t)(c2 * 8) * K + k0, &sm[buf][8192 + (wv * 16 + c2 * 8) * 64]);
  };
  const int sa = (lr & 7) << 3;
  auto COMPUTE = [&](int buf) {
#pragma unroll
    for (int kk = 0; kk < 64; kk += 32) {
      s16x8 af[4], bf[2];
#pragma unroll
      for (int mt = 0; mt < 4; ++mt)
        af[mt] = *(const s16x8*)&sm[buf][(wr * 64 + 16 * mt + lr) * 64 + ((kk + 8 * lg) ^ sa)];
#pragma unroll
      for (int nt = 0; nt < 2; ++nt)
        bf[nt] = *(const s16x8*)&sm[buf][8192 + (wc * 32 + 16 * nt + lr) * 64 + ((kk + 8 * lg) ^ sa)];
#pragma unroll
      for (int mt = 0; mt < 4; ++mt)
#pragma unroll
        for (int nt = 0; nt < 2; ++nt)
          acc[mt][nt] = mfma32(af[mt], bf[nt], acc[mt][nt]);
    }
  };

  // Counted-vmcnt pipeline. Invariant at the waitcnt: the only loads that may
  // be outstanding are the 4 issued textually just above (this iter's STAGE) —
  // so vmcnt(4) guarantees the previous STAGE (which COMPUTE reads) retired.
  // gload_lds writes memory -> cannot cross the "memory"-clobber asm; loop is
  // not unrolled; sched_barrier(0) pins against rule-#18 hoisting.
  STAGE(0, 0);
  int cur = 0;
#pragma unroll 1
  for (int t = 0; t < 5; ++t) {
    STAGE(cur ^ 1, (t + 1) * 64);
    asm volatile("s_waitcnt vmcnt(4)" ::: "memory");
    __builtin_amdgcn_sched_barrier(0);
    __builtin_amdgcn_s_barrier();
    __builtin_amdgcn_sched_barrier(0);
    COMPUTE(cur);
    __builtin_amdgcn_sched_barrier(0);
    __builtin_amdgcn_s_barrier();  // all waves done reading buf cur before next STAGE writes it
    cur ^= 1;
  }
  asm volatile("s_waitcnt vmcnt(0)" ::: "memory");
  __builtin_amdgcn_sched_barrier(0);
  __builtin_amdgcn_s_barrier();
  __builtin_amdgcn_sched_barrier(0);
  COMPUTE(cur);  // cur == 1: final compute reads sm[1]; epilogue tile uses sm[0]

  const int crow = m0 + wr * 64 + 4 * lg;
  const int ccol = n0 + wc * 32 + lr;
  if constexpr (QKV_EPI) {
    const int sel = n0 / 384;  // block-uniform
    unsigned short* qkv = (unsigned short*)Cv;
    if (sel < 2) {
      unsigned short* tile = &sm[0][0];
#pragma unroll
      for (int nt = 0; nt < 2; ++nt) {
        const int cc = wc * 32 + 16 * nt + lr;
        const float bv = bias[n0 + cc];
#pragma unroll
        for (int mt = 0; mt < 4; ++mt) {
#pragma unroll
          for (int e = 0; e < 4; ++e) {
            const int r = wr * 64 + 16 * mt + 4 * lg + e;
            tile[r * 128 + (cc ^ ((r & 7) << 3))] = f2bf(acc[mt][nt][e] + bv);
          }
        }
      }
      __syncthreads();
      const int hbase = (n0 - sel * 384) >> 5;
      const int tr = wv * 16 + (lane >> 2);
      const int gtok = m0 + tr;
      const int w2 = gtok >> 6, t0r = gtok & 63;
#pragma unroll
      for (int hh = 0; hh < 4; ++hh) {
        const int chunk = hh * 4 + (lane & 3);
        s16x8 v = *(const s16x8*)&tile[tr * 128 + ((chunk * 8) ^ ((tr & 7) << 3))];
        unsigned short* dst = qkv + (((size_t)w2 * 12 + hbase + hh) * 3 + sel) * 2048 +
                              t0r * 32 + (lane & 3) * 8;
        *(s16x8*)dst = v;
      }
    } else {
      const int window = crow >> 6;
      const int t0 = crow & 63;
#pragma unroll
      for (int nt = 0; nt < 2; ++nt) {
        const int col = ccol + 16 * nt;
        const int hcol = col - 768;
        const int h = hcol >> 5, d = hcol & 31;
        const float bv = bias[col];
        unsigned short* base = qkv + (((size_t)window * 12 + h) * 3 + 2) * 2048;
#pragma unroll
        for (int mt = 0; mt < 4; ++mt) {
          s16x4 pk;
#pragma unroll
          for (int e = 0; e < 4; ++e) pk[e] = (short)f2bf(acc[mt][nt][e] + bv);
          *(s16x4*)&base[d * 64 + t0 + 16 * mt] = pk;
        }
      }
    }
  } else {
    float* C = (float*)Cv;
#pragma unroll
    for (int mt = 0; mt < 4; ++mt)
#pragma unroll
      for (int nt = 0; nt < 2; ++nt) {
        const int col = ccol + 16 * nt;
        const float bv = bias[col];
#pragma unroll
        for (int e = 0; e < 4; ++e)
          C[(size_t)(crow + 16 * mt + e) * N + col] = acc[mt][nt][e] + bv;
      }
  }
}

// ---------------- attention: one wave per (window, head), no LDS (R8 form) ---------
__global__ __launch_bounds__(256) void attn_k(const unsigned short* __restrict__ qkv,
                                              const float* __restrict__ biasF,
                                              unsigned short* __restrict__ attnout) {
  const int lane = threadIdx.x & 63;
  const int wv = threadIdx.x >> 6;
  const int wh = blockIdx.x * 4 + wv;  // [0, 24576)
  const int window = wh / 12;
  const int h = wh - window * 12;
  const int lg = lane >> 4, lr = lane & 15;

  const unsigned short* hb = qkv + (size_t)wh * 6144;
  const unsigned short* Qh = hb;
  const unsigned short* Kh = hb + 2048;
  const unsigned short* Vth = hb + 4096;

  s16x8 ka[4], qb[4];
#pragma unroll
  for (int jt = 0; jt < 4; ++jt)
    ka[jt] = *(const s16x8*)&Kh[(jt * 16 + lr) * 32 + 8 * lg];
#pragma unroll
  for (int it = 0; it < 4; ++it)
    qb[it] = *(const s16x8*)&Qh[(it * 16 + lr) * 32 + 8 * lg];

  f32x4 c[4][4];
#pragma unroll
  for (int a = 0; a < 4; ++a)
#pragma unroll
    for (int b2 = 0; b2 < 4; ++b2) c[a][b2] = zero4();

#pragma unroll
  for (int jt = 0; jt < 4; ++jt)
#pragma unroll
    for (int it = 0; it < 4; ++it)
      c[jt][it] = mfma32(ka[jt], qb[it], c[jt][it]);

  const f32x4* bF = (const f32x4*)biasF + ((size_t)h * 16) * 64 + lane;
#pragma unroll
  for (int jt = 0; jt < 4; ++jt)
#pragma unroll
    for (int it = 0; it < 4; ++it)
      c[jt][it] += bF[(jt * 4 + it) * 64];

  s16x4 pb[4][4];
#pragma unroll
  for (int it = 0; it < 4; ++it) {
    float m = -3.0e38f;
#pragma unroll
    for (int jt = 0; jt < 4; ++jt)
#pragma unroll
      for (int e = 0; e < 4; ++e) m = fmaxf(m, c[jt][it][e]);
    m = fmaxf(m, __shfl_xor(m, 16));
    m = fmaxf(m, __shfl_xor(m, 32));
    float s = 0.f;
#pragma unroll
    for (int jt = 0; jt < 4; ++jt)
#pragma unroll
      for (int e = 0; e < 4; ++e) {
        float p = __expf(c[jt][it][e] - m);
        c[jt][it][e] = p;
        s += p;
      }
    s += __shfl_xor(s, 16);
    s += __shfl_xor(s, 32);
    const float inv = 1.f / s;
#pragma unroll
    for (int jt = 0; jt < 4; ++jt) {
      s16x4 pk;
#pragma unroll
      for (int e = 0; e < 4; ++e) pk[e] = (short)f2bf(c[jt][it][e] * inv);
      pb[jt][it] = pk;
    }
  }

  f32x4 o[2][4];
#pragma unroll
  for (int a = 0; a < 2; ++a)
#pragma unroll
    for (int b2 = 0; b2 < 4; ++b2) o[a][b2] = zero4();

#pragma unroll
  for (int jt = 0; jt < 4; ++jt) {
    s16x4 va[2];
#pragma unroll
    for (int dt = 0; dt < 2; ++dt)
      va[dt] = *(const s16x4*)&Vth[(dt * 16 + lr) * 64 + jt * 16 + 4 * lg];
#pragma unroll
    for (int dt = 0; dt < 2; ++dt)
#pragma unroll
      for (int it = 0; it < 4; ++it)
        o[dt][it] = mfma16(va[dt], pb[jt][it], o[dt][it]);
  }

  unsigned short* ob = attnout + (size_t)window * 64 * 384;
#pragma unroll
  for (int dt = 0; dt < 2; ++dt)
#pragma unroll
    for (int it = 0; it < 4; ++it) {
      s16x4 pk;
#pragma unroll
      for (int e = 0; e < 4; ++e) pk[e] = (short)f2bf(o[dt][it][e]);
      *(s16x4*)&ob[(size_t)(it * 16 + lr) * 384 + h * 32 + dt * 16 + 4 * lg] = pk;
    }
}

extern "C" void kernel_launch(void* const* d_in, const int* in_sizes, int n_in,
                              void* d_out, int out_size, void* d_ws, size_t ws_size,
                              hipStream_t stream) {
  const float* x = (const float*)d_in[0];
  const float* Wqkv = (const float*)d_in[1];
  const float* bqkv = (const float*)d_in[2];
  const float* Wm = (const float*)d_in[3];
  const float* bm = (const float*)d_in[4];
  const float* rel = (const float*)d_in[5];

  const size_t M = 131072;  // B*G*P
  char* ws = (char*)d_ws;
  size_t off = 0;
  unsigned short* qkv = (unsigned short*)(ws + off);   off += M * 1152 * 2;  // 302 MB
  unsigned short* xb = (unsigned short*)(ws + off);    off += M * 384 * 2;   // 100 MB (reused as attnout)
  unsigned short* WqkvT = (unsigned short*)(ws + off); off += 1152 * 384 * 2;
  unsigned short* WmT = (unsigned short*)(ws + off);   off += 384 * 384 * 2;
  float* biasF = (float*)(ws + off);                   off += 12 * 16 * 64 * 4 * 4;
  float* bqkvs = (float*)(ws + off);                   off += 1152 * 4;
  unsigned short* attnout = xb;  // xb is dead after gemm1

  if (ws_size < off) {
    fill_val<<<(out_size + 255) / 256, 256, 0, stream>>>((float*)d_out, out_size, 12345.0f);
    return;
  }

  prep_wqkvT<<<(1152 * 384 + 255) / 256, 256, 0, stream>>>(Wqkv, WqkvT);
  prep_wmT<<<(384 * 384 + 255) / 256, 256, 0, stream>>>(Wm, WmT);
  prep_bqkv<<<5, 256, 0, stream>>>(bqkv, bqkvs);
  prep_biasF<<<48, 256, 0, stream>>>(rel, biasF);
  conv_bf16<<<2048, 256, 0, stream>>>(x, xb);

  gemm_k<true><<<9216, 512, 0, stream>>>(xb, WqkvT, bqkvs, qkv);
  attn_k<<<6144, 256, 0, stream>>>(qkv, biasF, attnout);
  gemm_k<false><<<3072, 512, 0, stream>>>(attnout, WmT, bm, d_out);
}

// Round 13
// 447.083 us; speedup vs baseline: 1.1818x; 1.0271x over previous
//
#include <hip/hip_runtime.h>
#include <stdint.h>

// Round 13: R12 compute kernels FROZEN (best verified: 459us; gemm1 194us with
// counted-vmcnt+T2, attn R8-form, gemm2 R12-form). New: conv_bf16 + 4 prep
// kernels merged into ONE prep_all dispatch (block-range partition, disjoint
// reads/writes) -> 6 dispatches become 2 before attn, killing ~4 launch gaps
// and small-kernel tails.

typedef __attribute__((ext_vector_type(4))) float f32x4;
typedef __attribute__((ext_vector_type(4))) short s16x4;
typedef __attribute__((ext_vector_type(8))) short s16x8;

#define DEVI static __device__ __forceinline__

DEVI unsigned short f2bf(float f) {
  union { float f; uint32_t u; } v; v.f = f;
  return (unsigned short)((v.u + 0x7FFFu + ((v.u >> 16) & 1u)) >> 16);
}

DEVI f32x4 zero4() { f32x4 z; z[0] = 0.f; z[1] = 0.f; z[2] = 0.f; z[3] = 0.f; return z; }

#if defined(__has_builtin)
#if __has_builtin(__builtin_amdgcn_mfma_f32_16x16x16bf16_1k)
#define MFMA16_BUILTIN 1
#endif
#if __has_builtin(__builtin_amdgcn_global_load_lds)
#define HAS_GLLDS 1
#endif
#endif

DEVI f32x4 mfma16(s16x4 a, s16x4 b, f32x4 c) {
#ifdef MFMA16_BUILTIN
  return __builtin_amdgcn_mfma_f32_16x16x16bf16_1k(a, b, c, 0, 0, 0);
#else
  asm volatile("v_mfma_f32_16x16x16_bf16 %0, %1, %2, %0" : "+v"(c) : "v"(a), "v"(b));
  return c;
#endif
}

DEVI f32x4 mfma32(s16x8 a, s16x8 b, f32x4 c) {
  return __builtin_amdgcn_mfma_f32_16x16x32_bf16(a, b, c, 0, 0, 0);
}

DEVI void stage1k(const unsigned short* g_lane, unsigned short* lds_base) {
#ifdef HAS_GLLDS
  __builtin_amdgcn_global_load_lds(
      (const __attribute__((address_space(1))) unsigned int*)g_lane,
      (__attribute__((address_space(3))) unsigned int*)lds_base, 16, 0, 0);
#else
  *(s16x8*)(lds_base + (threadIdx.x & 63) * 8) = *(const s16x8*)g_lane;
#endif
}

__global__ void fill_val(float* o, int n, float v) {
  int t = blockIdx.x * 256 + threadIdx.x;
  if (t < n) o[t] = v;
}

// ---------------- merged prep: conv + wqkvT + wmT + bqkv + biasF ----------------
// Block partition (all branches block-uniform; reads/writes disjoint):
//   [0,2048)       conv: x fp32 -> xb bf16 (grid-stride, 12 chunks/thread)
//   2048           bqkvs (1152)
//   [2049,2097)    biasF (12288 threads)
//   [2097,2673)    WmT (147456 = 576*256)
//   [2673,4401)    WqkvT (442368 = 1728*256)
__global__ __launch_bounds__(256) void prep_all(
    const float* __restrict__ x, unsigned short* __restrict__ xb,
    const float* __restrict__ Wqkv, unsigned short* __restrict__ WqkvT,
    const float* __restrict__ Wm, unsigned short* __restrict__ WmT,
    const float* __restrict__ bqkv, float* __restrict__ bqkvs,
    const float* __restrict__ rel, float* __restrict__ biasF) {
  const int b = blockIdx.x;
  if (b < 2048) {
    const size_t nchunk = 131072UL * 384 / 8;
    for (size_t i = (size_t)b * 256 + threadIdx.x; i < nchunk; i += 2048UL * 256) {
      f32x4 a = *(const f32x4*)(x + i * 8);
      f32x4 c = *(const f32x4*)(x + i * 8 + 4);
      s16x8 p;
      p[0] = (short)f2bf(a[0]); p[1] = (short)f2bf(a[1]);
      p[2] = (short)f2bf(a[2]); p[3] = (short)f2bf(a[3]);
      p[4] = (short)f2bf(c[0]); p[5] = (short)f2bf(c[1]);
      p[6] = (short)f2bf(c[2]); p[7] = (short)f2bf(c[3]);
      *(s16x8*)(xb + i * 8) = p;
    }
  } else if (b == 2048) {
    for (int t = threadIdx.x; t < 1152; t += 256)
      bqkvs[t] = bqkv[t] * ((t < 384) ? 0.17677669529663687f : 1.0f);
  } else if (b < 2097) {
    int t = (b - 2049) * 256 + threadIdx.x;  // 12288 = 12*16*64
    if (t < 12288) {
      int h = t >> 10;
      int r = (t >> 6) & 15;
      int lane = t & 63;
      int jt = r >> 2, it = r & 3;
      int lg = lane >> 4, lr = lane & 15;
      int i = it * 16 + lr;
#pragma unroll
      for (int e = 0; e < 4; ++e) {
        int j = jt * 16 + lg * 4 + e;
        int idx = ((i >> 3) - (j >> 3) + 7) * 15 + ((i & 7) - (j & 7) + 7);
        biasF[t * 4 + e] = rel[idx * 12 + h];
      }
    }
  } else if (b < 2673) {
    int t = (b - 2097) * 256 + threadIdx.x;  // 147456 exactly
    int n = t / 384, k = t - n * 384;
    WmT[t] = f2bf(Wm[(size_t)k * 384 + n]);
  } else {
    int t = (b - 2673) * 256 + threadIdx.x;  // 442368 exactly
    int n = t / 384, k = t - n * 384;
    float s = (n < 384) ? 0.17677669529663687f : 1.0f;  // SCALE folded into Wq
    WqkvT[t] = f2bf(Wqkv[(size_t)k * 1152 + n] * s);
  }
}

// ---------------- GEMM (8 waves, counted-vmcnt dbuf + T2 swizzle) — R12 verbatim ----
template <bool QKV_EPI>
__global__ __launch_bounds__(512, 4) void gemm_k(const unsigned short* __restrict__ A,
                                                 const unsigned short* __restrict__ BT,
                                                 const float* __restrict__ bias,
                                                 void* __restrict__ Cv) {
  constexpr int K = 384;
  constexpr int NT = QKV_EPI ? 9 : 3;
  constexpr int N = NT * 128;
  __shared__ unsigned short sm[2][16384];
  const int bid = blockIdx.x;
  const int swz = (bid & 7) * (NT * 128) + (bid >> 3);  // XCD-aware, bijective
  const int n0 = (swz % NT) * 128;
  const int m0 = (swz / NT) * 128;
  const int tid = threadIdx.x;
  const int lane = tid & 63, wv = tid >> 6;       // wv 0..7
  const int wr = wv >> 2, wc = wv & 3;            // wave grid 2x4: 64 rows x 32 cols
  const int lg = lane >> 4, lr = lane & 15;

  const int scol = ((lane & 7) ^ (lane >> 3)) * 8;
  const unsigned short* Ag = A + (size_t)(m0 + wv * 16 + (lane >> 3)) * K + scol;
  const unsigned short* Bg = BT + (size_t)(n0 + wv * 16 + (lane >> 3)) * K + scol;

  f32x4 acc[4][2];
#pragma unroll
  for (int i = 0; i < 4; ++i)
#pragma unroll
    for (int j = 0; j < 2; ++j) acc[i][j] = zero4();

  auto STAGE = [&](int buf, int k0) {  // 4 gload_lds per thread
#pragma unroll
    for (int c2 = 0; c2 < 2; ++c2)
      stage1k(Ag + (size_t)(c2 * 8) * K + k0, &sm[buf][(wv * 16 + c2 * 8) * 64]);
#pragma unroll
    for (int c2 = 0; c2 < 2; ++c2)
      stage1k(Bg + (size_t)(c2 * 8) * K + k0, &sm[buf][8192 + (wv * 16 + c2 * 8) * 64]);
  };
  const int sa = (lr & 7) << 3;
  auto COMPUTE = [&](int buf) {
#pragma unroll
    for (int kk = 0; kk < 64; kk += 32) {
      s16x8 af[4], bf[2];
#pragma unroll
      for (int mt = 0; mt < 4; ++mt)
        af[mt] = *(const s16x8*)&sm[buf][(wr * 64 + 16 * mt + lr) * 64 + ((kk + 8 * lg) ^ sa)];
#pragma unroll
      for (int nt = 0; nt < 2; ++nt)
        bf[nt] = *(const s16x8*)&sm[buf][8192 + (wc * 32 + 16 * nt + lr) * 64 + ((kk + 8 * lg) ^ sa)];
#pragma unroll
      for (int mt = 0; mt < 4; ++mt)
#pragma unroll
        for (int nt = 0; nt < 2; ++nt)
          acc[mt][nt] = mfma32(af[mt], bf[nt], acc[mt][nt]);
    }
  };

  // Counted-vmcnt pipeline (R12-verified). Invariant at the waitcnt: only this
  // iter's 4 STAGE loads may be outstanding -> previous STAGE retired.
  STAGE(0, 0);
  int cur = 0;
#pragma unroll 1
  for (int t = 0; t < 5; ++t) {
    STAGE(cur ^ 1, (t + 1) * 64);
    asm volatile("s_waitcnt vmcnt(4)" ::: "memory");
    __builtin_amdgcn_sched_barrier(0);
    __builtin_amdgcn_s_barrier();
    __builtin_amdgcn_sched_barrier(0);
    COMPUTE(cur);
    __builtin_amdgcn_sched_barrier(0);
    __builtin_amdgcn_s_barrier();
    cur ^= 1;
  }
  asm volatile("s_waitcnt vmcnt(0)" ::: "memory");
  __builtin_amdgcn_sched_barrier(0);
  __builtin_amdgcn_s_barrier();
  __builtin_amdgcn_sched_barrier(0);
  COMPUTE(cur);  // cur == 1: final compute reads sm[1]; epilogue tile uses sm[0]

  const int crow = m0 + wr * 64 + 4 * lg;
  const int ccol = n0 + wc * 32 + lr;
  if constexpr (QKV_EPI) {
    const int sel = n0 / 384;  // block-uniform
    unsigned short* qkv = (unsigned short*)Cv;
    if (sel < 2) {
      unsigned short* tile = &sm[0][0];
#pragma unroll
      for (int nt = 0; nt < 2; ++nt) {
        const int cc = wc * 32 + 16 * nt + lr;
        const float bv = bias[n0 + cc];
#pragma unroll
        for (int mt = 0; mt < 4; ++mt) {
#pragma unroll
          for (int e = 0; e < 4; ++e) {
            const int r = wr * 64 + 16 * mt + 4 * lg + e;
            tile[r * 128 + (cc ^ ((r & 7) << 3))] = f2bf(acc[mt][nt][e] + bv);
          }
        }
      }
      __syncthreads();
      const int hbase = (n0 - sel * 384) >> 5;
      const int tr = wv * 16 + (lane >> 2);
      const int gtok = m0 + tr;
      const int w2 = gtok >> 6, t0r = gtok & 63;
#pragma unroll
      for (int hh = 0; hh < 4; ++hh) {
        const int chunk = hh * 4 + (lane & 3);
        s16x8 v = *(const s16x8*)&tile[tr * 128 + ((chunk * 8) ^ ((tr & 7) << 3))];
        unsigned short* dst = qkv + (((size_t)w2 * 12 + hbase + hh) * 3 + sel) * 2048 +
                              t0r * 32 + (lane & 3) * 8;
        *(s16x8*)dst = v;
      }
    } else {
      const int window = crow >> 6;
      const int t0 = crow & 63;
#pragma unroll
      for (int nt = 0; nt < 2; ++nt) {
        const int col = ccol + 16 * nt;
        const int hcol = col - 768;
        const int h = hcol >> 5, d = hcol & 31;
        const float bv = bias[col];
        unsigned short* base = qkv + (((size_t)window * 12 + h) * 3 + 2) * 2048;
#pragma unroll
        for (int mt = 0; mt < 4; ++mt) {
          s16x4 pk;
#pragma unroll
          for (int e = 0; e < 4; ++e) pk[e] = (short)f2bf(acc[mt][nt][e] + bv);
          *(s16x4*)&base[d * 64 + t0 + 16 * mt] = pk;
        }
      }
    }
  } else {
    float* C = (float*)Cv;
#pragma unroll
    for (int mt = 0; mt < 4; ++mt)
#pragma unroll
      for (int nt = 0; nt < 2; ++nt) {
        const int col = ccol + 16 * nt;
        const float bv = bias[col];
#pragma unroll
        for (int e = 0; e < 4; ++e)
          C[(size_t)(crow + 16 * mt + e) * N + col] = acc[mt][nt][e] + bv;
      }
  }
}

// ---------------- attention: one wave per (window, head), no LDS (R8 form) ---------
__global__ __launch_bounds__(256) void attn_k(const unsigned short* __restrict__ qkv,
                                              const float* __restrict__ biasF,
                                              unsigned short* __restrict__ attnout) {
  const int lane = threadIdx.x & 63;
  const int wv = threadIdx.x >> 6;
  const int wh = blockIdx.x * 4 + wv;  // [0, 24576)
  const int window = wh / 12;
  const int h = wh - window * 12;
  const int lg = lane >> 4, lr = lane & 15;

  const unsigned short* hb = qkv + (size_t)wh * 6144;
  const unsigned short* Qh = hb;
  const unsigned short* Kh = hb + 2048;
  const unsigned short* Vth = hb + 4096;

  s16x8 ka[4], qb[4];
#pragma unroll
  for (int jt = 0; jt < 4; ++jt)
    ka[jt] = *(const s16x8*)&Kh[(jt * 16 + lr) * 32 + 8 * lg];
#pragma unroll
  for (int it = 0; it < 4; ++it)
    qb[it] = *(const s16x8*)&Qh[(it * 16 + lr) * 32 + 8 * lg];

  f32x4 c[4][4];
#pragma unroll
  for (int a = 0; a < 4; ++a)
#pragma unroll
    for (int b2 = 0; b2 < 4; ++b2) c[a][b2] = zero4();

#pragma unroll
  for (int jt = 0; jt < 4; ++jt)
#pragma unroll
    for (int it = 0; it < 4; ++it)
      c[jt][it] = mfma32(ka[jt], qb[it], c[jt][it]);

  const f32x4* bF = (const f32x4*)biasF + ((size_t)h * 16) * 64 + lane;
#pragma unroll
  for (int jt = 0; jt < 4; ++jt)
#pragma unroll
    for (int it = 0; it < 4; ++it)
      c[jt][it] += bF[(jt * 4 + it) * 64];

  s16x4 pb[4][4];
#pragma unroll
  for (int it = 0; it < 4; ++it) {
    float m = -3.0e38f;
#pragma unroll
    for (int jt = 0; jt < 4; ++jt)
#pragma unroll
      for (int e = 0; e < 4; ++e) m = fmaxf(m, c[jt][it][e]);
    m = fmaxf(m, __shfl_xor(m, 16));
    m = fmaxf(m, __shfl_xor(m, 32));
    float s = 0.f;
#pragma unroll
    for (int jt = 0; jt < 4; ++jt)
#pragma unroll
      for (int e = 0; e < 4; ++e) {
        float p = __expf(c[jt][it][e] - m);
        c[jt][it][e] = p;
        s += p;
      }
    s += __shfl_xor(s, 16);
    s += __shfl_xor(s, 32);
    const float inv = 1.f / s;
#pragma unroll
    for (int jt = 0; jt < 4; ++jt) {
      s16x4 pk;
#pragma unroll
      for (int e = 0; e < 4; ++e) pk[e] = (short)f2bf(c[jt][it][e] * inv);
      pb[jt][it] = pk;
    }
  }

  f32x4 o[2][4];
#pragma unroll
  for (int a = 0; a < 2; ++a)
#pragma unroll
    for (int b2 = 0; b2 < 4; ++b2) o[a][b2] = zero4();

#pragma unroll
  for (int jt = 0; jt < 4; ++jt) {
    s16x4 va[2];
#pragma unroll
    for (int dt = 0; dt < 2; ++dt)
      va[dt] = *(const s16x4*)&Vth[(dt * 16 + lr) * 64 + jt * 16 + 4 * lg];
#pragma unroll
    for (int dt = 0; dt < 2; ++dt)
#pragma unroll
      for (int it = 0; it < 4; ++it)
        o[dt][it] = mfma16(va[dt], pb[jt][it], o[dt][it]);
  }

  unsigned short* ob = attnout + (size_t)window * 64 * 384;
#pragma unroll
  for (int dt = 0; dt < 2; ++dt)
#pragma unroll
    for (int it = 0; it < 4; ++it) {
      s16x4 pk;
#pragma unroll
      for (int e = 0; e < 4; ++e) pk[e] = (short)f2bf(o[dt][it][e]);
      *(s16x4*)&ob[(size_t)(it * 16 + lr) * 384 + h * 32 + dt * 16 + 4 * lg] = pk;
    }
}

extern "C" void kernel_launch(void* const* d_in, const int* in_sizes, int n_in,
                              void* d_out, int out_size, void* d_ws, size_t ws_size,
                              hipStream_t stream) {
  const float* x = (const float*)d_in[0];
  const float* Wqkv = (const float*)d_in[1];
  const float* bqkv = (const float*)d_in[2];
  const float* Wm = (const float*)d_in[3];
  const float* bm = (const float*)d_in[4];
  const float* rel = (const float*)d_in[5];

  const size_t M = 131072;  // B*G*P
  char* ws = (char*)d_ws;
  size_t off = 0;
  unsigned short* qkv = (unsigned short*)(ws + off);   off += M * 1152 * 2;  // 302 MB
  unsigned short* xb = (unsigned short*)(ws + off);    off += M * 384 * 2;   // 100 MB (reused as attnout)
  unsigned short* WqkvT = (unsigned short*)(ws + off); off += 1152 * 384 * 2;
  unsigned short* WmT = (unsigned short*)(ws + off);   off += 384 * 384 * 2;
  float* biasF = (float*)(ws + off);                   off += 12 * 16 * 64 * 4 * 4;
  float* bqkvs = (float*)(ws + off);                   off += 1152 * 4;
  unsigned short* attnout = xb;  // xb is dead after gemm1

  if (ws_size < off) {
    fill_val<<<(out_size + 255) / 256, 256, 0, stream>>>((float*)d_out, out_size, 12345.0f);
    return;
  }

  prep_all<<<4401, 256, 0, stream>>>(x, xb, Wqkv, WqkvT, Wm, WmT, bqkv, bqkvs, rel, biasF);
  gemm_k<true><<<9216, 512, 0, stream>>>(xb, WqkvT, bqkvs, qkv);
  attn_k<<<6144, 256, 0, stream>>>(qkv, biasF, attnout);
  gemm_k<false><<<3072, 512, 0, stream>>>(attnout, WmT, bm, d_out);
}

// Round 14
// 442.471 us; speedup vs baseline: 1.1941x; 1.0104x over previous
//
#include <hip/hip_runtime.h>
#include <stdint.h>

// Round 14: R13 frozen (447us) except attn_k stores: in-register 4-lane
// transpose (shfl_xor 16/32/48 within lg-group) so each lane stores one
// s16x8 (16B) and each 4-lane group writes a full 64B line — replaces 16
// half-line (32B-segment) s16x4 stores that double-wrote every line.

typedef __attribute__((ext_vector_type(4))) float f32x4;
typedef __attribute__((ext_vector_type(4))) short s16x4;
typedef __attribute__((ext_vector_type(8))) short s16x8;

#define DEVI static __device__ __forceinline__

DEVI unsigned short f2bf(float f) {
  union { float f; uint32_t u; } v; v.f = f;
  return (unsigned short)((v.u + 0x7FFFu + ((v.u >> 16) & 1u)) >> 16);
}

DEVI uint32_t pk2(float lo, float hi) {  // [lo,hi] as 2 bf16 in one u32
  return (uint32_t)f2bf(lo) | ((uint32_t)f2bf(hi) << 16);
}

DEVI f32x4 zero4() { f32x4 z; z[0] = 0.f; z[1] = 0.f; z[2] = 0.f; z[3] = 0.f; return z; }

#if defined(__has_builtin)
#if __has_builtin(__builtin_amdgcn_mfma_f32_16x16x16bf16_1k)
#define MFMA16_BUILTIN 1
#endif
#if __has_builtin(__builtin_amdgcn_global_load_lds)
#define HAS_GLLDS 1
#endif
#endif

DEVI f32x4 mfma16(s16x4 a, s16x4 b, f32x4 c) {
#ifdef MFMA16_BUILTIN
  return __builtin_amdgcn_mfma_f32_16x16x16bf16_1k(a, b, c, 0, 0, 0);
#else
  asm volatile("v_mfma_f32_16x16x16_bf16 %0, %1, %2, %0" : "+v"(c) : "v"(a), "v"(b));
  return c;
#endif
}

DEVI f32x4 mfma32(s16x8 a, s16x8 b, f32x4 c) {
  return __builtin_amdgcn_mfma_f32_16x16x32_bf16(a, b, c, 0, 0, 0);
}

DEVI void stage1k(const unsigned short* g_lane, unsigned short* lds_base) {
#ifdef HAS_GLLDS
  __builtin_amdgcn_global_load_lds(
      (const __attribute__((address_space(1))) unsigned int*)g_lane,
      (__attribute__((address_space(3))) unsigned int*)lds_base, 16, 0, 0);
#else
  *(s16x8*)(lds_base + (threadIdx.x & 63) * 8) = *(const s16x8*)g_lane;
#endif
}

__global__ void fill_val(float* o, int n, float v) {
  int t = blockIdx.x * 256 + threadIdx.x;
  if (t < n) o[t] = v;
}

// ---------------- merged prep: conv + wqkvT + wmT + bqkv + biasF (R13) ----------------
__global__ __launch_bounds__(256) void prep_all(
    const float* __restrict__ x, unsigned short* __restrict__ xb,
    const float* __restrict__ Wqkv, unsigned short* __restrict__ WqkvT,
    const float* __restrict__ Wm, unsigned short* __restrict__ WmT,
    const float* __restrict__ bqkv, float* __restrict__ bqkvs,
    const float* __restrict__ rel, float* __restrict__ biasF) {
  const int b = blockIdx.x;
  if (b < 2048) {
    const size_t nchunk = 131072UL * 384 / 8;
    for (size_t i = (size_t)b * 256 + threadIdx.x; i < nchunk; i += 2048UL * 256) {
      f32x4 a = *(const f32x4*)(x + i * 8);
      f32x4 c = *(const f32x4*)(x + i * 8 + 4);
      s16x8 p;
      p[0] = (short)f2bf(a[0]); p[1] = (short)f2bf(a[1]);
      p[2] = (short)f2bf(a[2]); p[3] = (short)f2bf(a[3]);
      p[4] = (short)f2bf(c[0]); p[5] = (short)f2bf(c[1]);
      p[6] = (short)f2bf(c[2]); p[7] = (short)f2bf(c[3]);
      *(s16x8*)(xb + i * 8) = p;
    }
  } else if (b == 2048) {
    for (int t = threadIdx.x; t < 1152; t += 256)
      bqkvs[t] = bqkv[t] * ((t < 384) ? 0.17677669529663687f : 1.0f);
  } else if (b < 2097) {
    int t = (b - 2049) * 256 + threadIdx.x;  // 12288
    if (t < 12288) {
      int h = t >> 10;
      int r = (t >> 6) & 15;
      int lane = t & 63;
      int jt = r >> 2, it = r & 3;
      int lg = lane >> 4, lr = lane & 15;
      int i = it * 16 + lr;
#pragma unroll
      for (int e = 0; e < 4; ++e) {
        int j = jt * 16 + lg * 4 + e;
        int idx = ((i >> 3) - (j >> 3) + 7) * 15 + ((i & 7) - (j & 7) + 7);
        biasF[t * 4 + e] = rel[idx * 12 + h];
      }
    }
  } else if (b < 2673) {
    int t = (b - 2097) * 256 + threadIdx.x;  // 147456
    int n = t / 384, k = t - n * 384;
    WmT[t] = f2bf(Wm[(size_t)k * 384 + n]);
  } else {
    int t = (b - 2673) * 256 + threadIdx.x;  // 442368
    int n = t / 384, k = t - n * 384;
    float s = (n < 384) ? 0.17677669529663687f : 1.0f;
    WqkvT[t] = f2bf(Wqkv[(size_t)k * 1152 + n] * s);
  }
}

// ---------------- GEMM (8 waves, counted-vmcnt dbuf + T2 swizzle) — R12 verbatim ----
template <bool QKV_EPI>
__global__ __launch_bounds__(512, 4) void gemm_k(const unsigned short* __restrict__ A,
                                                 const unsigned short* __restrict__ BT,
                                                 const float* __restrict__ bias,
                                                 void* __restrict__ Cv) {
  constexpr int K = 384;
  constexpr int NT = QKV_EPI ? 9 : 3;
  constexpr int N = NT * 128;
  __shared__ unsigned short sm[2][16384];
  const int bid = blockIdx.x;
  const int swz = (bid & 7) * (NT * 128) + (bid >> 3);
  const int n0 = (swz % NT) * 128;
  const int m0 = (swz / NT) * 128;
  const int tid = threadIdx.x;
  const int lane = tid & 63, wv = tid >> 6;
  const int wr = wv >> 2, wc = wv & 3;
  const int lg = lane >> 4, lr = lane & 15;

  const int scol = ((lane & 7) ^ (lane >> 3)) * 8;
  const unsigned short* Ag = A + (size_t)(m0 + wv * 16 + (lane >> 3)) * K + scol;
  const unsigned short* Bg = BT + (size_t)(n0 + wv * 16 + (lane >> 3)) * K + scol;

  f32x4 acc[4][2];
#pragma unroll
  for (int i = 0; i < 4; ++i)
#pragma unroll
    for (int j = 0; j < 2; ++j) acc[i][j] = zero4();

  auto STAGE = [&](int buf, int k0) {
#pragma unroll
    for (int c2 = 0; c2 < 2; ++c2)
      stage1k(Ag + (size_t)(c2 * 8) * K + k0, &sm[buf][(wv * 16 + c2 * 8) * 64]);
#pragma unroll
    for (int c2 = 0; c2 < 2; ++c2)
      stage1k(Bg + (size_t)(c2 * 8) * K + k0, &sm[buf][8192 + (wv * 16 + c2 * 8) * 64]);
  };
  const int sa = (lr & 7) << 3;
  auto COMPUTE = [&](int buf) {
#pragma unroll
    for (int kk = 0; kk < 64; kk += 32) {
      s16x8 af[4], bf[2];
#pragma unroll
      for (int mt = 0; mt < 4; ++mt)
        af[mt] = *(const s16x8*)&sm[buf][(wr * 64 + 16 * mt + lr) * 64 + ((kk + 8 * lg) ^ sa)];
#pragma unroll
      for (int nt = 0; nt < 2; ++nt)
        bf[nt] = *(const s16x8*)&sm[buf][8192 + (wc * 32 + 16 * nt + lr) * 64 + ((kk + 8 * lg) ^ sa)];
#pragma unroll
      for (int mt = 0; mt < 4; ++mt)
#pragma unroll
        for (int nt = 0; nt < 2; ++nt)
          acc[mt][nt] = mfma32(af[mt], bf[nt], acc[mt][nt]);
    }
  };

  STAGE(0, 0);
  int cur = 0;
#pragma unroll 1
  for (int t = 0; t < 5; ++t) {
    STAGE(cur ^ 1, (t + 1) * 64);
    asm volatile("s_waitcnt vmcnt(4)" ::: "memory");
    __builtin_amdgcn_sched_barrier(0);
    __builtin_amdgcn_s_barrier();
    __builtin_amdgcn_sched_barrier(0);
    COMPUTE(cur);
    __builtin_amdgcn_sched_barrier(0);
    __builtin_amdgcn_s_barrier();
    cur ^= 1;
  }
  asm volatile("s_waitcnt vmcnt(0)" ::: "memory");
  __builtin_amdgcn_sched_barrier(0);
  __builtin_amdgcn_s_barrier();
  __builtin_amdgcn_sched_barrier(0);
  COMPUTE(cur);

  const int crow = m0 + wr * 64 + 4 * lg;
  const int ccol = n0 + wc * 32 + lr;
  if constexpr (QKV_EPI) {
    const int sel = n0 / 384;
    unsigned short* qkv = (unsigned short*)Cv;
    if (sel < 2) {
      unsigned short* tile = &sm[0][0];
#pragma unroll
      for (int nt = 0; nt < 2; ++nt) {
        const int cc = wc * 32 + 16 * nt + lr;
        const float bv = bias[n0 + cc];
#pragma unroll
        for (int mt = 0; mt < 4; ++mt) {
#pragma unroll
          for (int e = 0; e < 4; ++e) {
            const int r = wr * 64 + 16 * mt + 4 * lg + e;
            tile[r * 128 + (cc ^ ((r & 7) << 3))] = f2bf(acc[mt][nt][e] + bv);
          }
        }
      }
      __syncthreads();
      const int hbase = (n0 - sel * 384) >> 5;
      const int tr = wv * 16 + (lane >> 2);
      const int gtok = m0 + tr;
      const int w2 = gtok >> 6, t0r = gtok & 63;
#pragma unroll
      for (int hh = 0; hh < 4; ++hh) {
        const int chunk = hh * 4 + (lane & 3);
        s16x8 v = *(const s16x8*)&tile[tr * 128 + ((chunk * 8) ^ ((tr & 7) << 3))];
        unsigned short* dst = qkv + (((size_t)w2 * 12 + hbase + hh) * 3 + sel) * 2048 +
                              t0r * 32 + (lane & 3) * 8;
        *(s16x8*)dst = v;
      }
    } else {
      const int window = crow >> 6;
      const int t0 = crow & 63;
#pragma unroll
      for (int nt = 0; nt < 2; ++nt) {
        const int col = ccol + 16 * nt;
        const int hcol = col - 768;
        const int h = hcol >> 5, d = hcol & 31;
        const float bv = bias[col];
        unsigned short* base = qkv + (((size_t)window * 12 + h) * 3 + 2) * 2048;
#pragma unroll
        for (int mt = 0; mt < 4; ++mt) {
          s16x4 pk;
#pragma unroll
          for (int e = 0; e < 4; ++e) pk[e] = (short)f2bf(acc[mt][nt][e] + bv);
          *(s16x4*)&base[d * 64 + t0 + 16 * mt] = pk;
        }
      }
    }
  } else {
    float* C = (float*)Cv;
#pragma unroll
    for (int mt = 0; mt < 4; ++mt)
#pragma unroll
      for (int nt = 0; nt < 2; ++nt) {
        const int col = ccol + 16 * nt;
        const float bv = bias[col];
#pragma unroll
        for (int e = 0; e < 4; ++e)
          C[(size_t)(crow + 16 * mt + e) * N + col] = acc[mt][nt][e] + bv;
      }
  }
}

// ---------------- attention: one wave per (window, head); transposed 64B stores ------
__global__ __launch_bounds__(256) void attn_k(const unsigned short* __restrict__ qkv,
                                              const float* __restrict__ biasF,
                                              unsigned short* __restrict__ attnout) {
  const int lane = threadIdx.x & 63;
  const int wv = threadIdx.x >> 6;
  const int wh = blockIdx.x * 4 + wv;  // [0, 24576)
  const int window = wh / 12;
  const int h = wh - window * 12;
  const int lg = lane >> 4, lr = lane & 15;

  const unsigned short* hb = qkv + (size_t)wh * 6144;
  const unsigned short* Qh = hb;
  const unsigned short* Kh = hb + 2048;
  const unsigned short* Vth = hb + 4096;

  s16x8 ka[4], qb[4];
#pragma unroll
  for (int jt = 0; jt < 4; ++jt)
    ka[jt] = *(const s16x8*)&Kh[(jt * 16 + lr) * 32 + 8 * lg];
#pragma unroll
  for (int it = 0; it < 4; ++it)
    qb[it] = *(const s16x8*)&Qh[(it * 16 + lr) * 32 + 8 * lg];

  f32x4 c[4][4];
#pragma unroll
  for (int a = 0; a < 4; ++a)
#pragma unroll
    for (int b2 = 0; b2 < 4; ++b2) c[a][b2] = zero4();

#pragma unroll
  for (int jt = 0; jt < 4; ++jt)
#pragma unroll
    for (int it = 0; it < 4; ++it)
      c[jt][it] = mfma32(ka[jt], qb[it], c[jt][it]);

  const f32x4* bF = (const f32x4*)biasF + ((size_t)h * 16) * 64 + lane;
#pragma unroll
  for (int jt = 0; jt < 4; ++jt)
#pragma unroll
    for (int it = 0; it < 4; ++it)
      c[jt][it] += bF[(jt * 4 + it) * 64];

  s16x4 pb[4][4];
#pragma unroll
  for (int it = 0; it < 4; ++it) {
    float m = -3.0e38f;
#pragma unroll
    for (int jt = 0; jt < 4; ++jt)
#pragma unroll
      for (int e = 0; e < 4; ++e) m = fmaxf(m, c[jt][it][e]);
    m = fmaxf(m, __shfl_xor(m, 16));
    m = fmaxf(m, __shfl_xor(m, 32));
    float s = 0.f;
#pragma unroll
    for (int jt = 0; jt < 4; ++jt)
#pragma unroll
      for (int e = 0; e < 4; ++e) {
        float p = __expf(c[jt][it][e] - m);
        c[jt][it][e] = p;
        s += p;
      }
    s += __shfl_xor(s, 16);
    s += __shfl_xor(s, 32);
    const float inv = 1.f / s;
#pragma unroll
    for (int jt = 0; jt < 4; ++jt) {
      s16x4 pk;
#pragma unroll
      for (int e = 0; e < 4; ++e) pk[e] = (short)f2bf(c[jt][it][e] * inv);
      pb[jt][it] = pk;
    }
  }

  f32x4 o[2][4];
#pragma unroll
  for (int a = 0; a < 2; ++a)
#pragma unroll
    for (int b2 = 0; b2 < 4; ++b2) o[a][b2] = zero4();

#pragma unroll
  for (int jt = 0; jt < 4; ++jt) {
    s16x4 va[2];
#pragma unroll
    for (int dt = 0; dt < 2; ++dt)
      va[dt] = *(const s16x4*)&Vth[(dt * 16 + lr) * 64 + jt * 16 + 4 * lg];
#pragma unroll
    for (int dt = 0; dt < 2; ++dt)
#pragma unroll
      for (int it = 0; it < 4; ++it)
        o[dt][it] = mfma16(va[dt], pb[jt][it], o[dt][it]);
  }

  // ---- transposed store: lg-group 4-lane exchange so lane lg holds d[8lg,8lg+8)
  // of token it*16+lr; one s16x8 (16B) store per (lane,it); 4 lanes = 64B line.
  // P(lg) = d[4lg..4lg+3] (o[0]), Q(lg) = d[16+4lg..16+4lg+3] (o[1]).
  // lg0=[P0,P1] lg1=[P2,P3] lg2=[Q0,Q1] lg3=[Q2,Q3]:
  //   P1: l1->l0 (x16); Q2: l2->l3 (x16); P3: l3->l1 (x32); Q0: l0->l2 (x32);
  //   P2: l2->l1 (x48); Q1: l1->l2 (x48).
  unsigned short* ob = attnout + (size_t)window * 64 * 384;
#pragma unroll
  for (int it = 0; it < 4; ++it) {
    const uint32_t p0 = pk2(o[0][it][0], o[0][it][1]);
    const uint32_t p1 = pk2(o[0][it][2], o[0][it][3]);
    const uint32_t q0 = pk2(o[1][it][0], o[1][it][1]);
    const uint32_t q1 = pk2(o[1][it][2], o[1][it][3]);

    const uint32_t x16_0 = __shfl_xor((int)(lg == 2 ? q0 : p0), 16);
    const uint32_t x16_1 = __shfl_xor((int)(lg == 2 ? q1 : p1), 16);
    const uint32_t x32_0 = __shfl_xor((int)(lg == 0 ? q0 : p0), 32);
    const uint32_t x32_1 = __shfl_xor((int)(lg == 0 ? q1 : p1), 32);
    const uint32_t x48_0 = __shfl_xor((int)(lg == 1 ? q0 : p0), 48);
    const uint32_t x48_1 = __shfl_xor((int)(lg == 1 ? q1 : p1), 48);

    uint32_t w[4];
    w[0] = lg == 0 ? p0 : lg == 1 ? x48_0 : lg == 2 ? x32_0 : x16_0;
    w[1] = lg == 0 ? p1 : lg == 1 ? x48_1 : lg == 2 ? x32_1 : x16_1;
    w[2] = lg == 0 ? x16_0 : lg == 1 ? x32_0 : lg == 2 ? x48_0 : q0;
    w[3] = lg == 0 ? x16_1 : lg == 1 ? x32_1 : lg == 2 ? x48_1 : q1;

    *(uint4*)&ob[(size_t)(it * 16 + lr) * 384 + h * 32 + 8 * lg] =
        make_uint4(w[0], w[1], w[2], w[3]);
  }
}

extern "C" void kernel_launch(void* const* d_in, const int* in_sizes, int n_in,
                              void* d_out, int out_size, void* d_ws, size_t ws_size,
                              hipStream_t stream) {
  const float* x = (const float*)d_in[0];
  const float* Wqkv = (const float*)d_in[1];
  const float* bqkv = (const float*)d_in[2];
  const float* Wm = (const float*)d_in[3];
  const float* bm = (const float*)d_in[4];
  const float* rel = (const float*)d_in[5];

  const size_t M = 131072;  // B*G*P
  char* ws = (char*)d_ws;
  size_t off = 0;
  unsigned short* qkv = (unsigned short*)(ws + off);   off += M * 1152 * 2;  // 302 MB
  unsigned short* xb = (unsigned short*)(ws + off);    off += M * 384 * 2;   // 100 MB (reused as attnout)
  unsigned short* WqkvT = (unsigned short*)(ws + off); off += 1152 * 384 * 2;
  unsigned short* WmT = (unsigned short*)(ws + off);   off += 384 * 384 * 2;
  float* biasF = (float*)(ws + off);                   off += 12 * 16 * 64 * 4 * 4;
  float* bqkvs = (float*)(ws + off);                   off += 1152 * 4;
  unsigned short* attnout = xb;  // xb is dead after gemm1

  if (ws_size < off) {
    fill_val<<<(out_size + 255) / 256, 256, 0, stream>>>((float*)d_out, out_size, 12345.0f);
    return;
  }

  prep_all<<<4401, 256, 0, stream>>>(x, xb, Wqkv, WqkvT, Wm, WmT, bqkv, bqkvs, rel, biasF);
  gemm_k<true><<<9216, 512, 0, stream>>>(xb, WqkvT, bqkvs, qkv);
  attn_k<<<6144, 256, 0, stream>>>(qkv, biasF, attnout);
  gemm_k<false><<<3072, 512, 0, stream>>>(attnout, WmT, bm, d_out);
}

// Round 15
// 424.081 us; speedup vs baseline: 1.2459x; 1.0434x over previous
//
#include <hip/hip_runtime.h>
#include <stdint.h>

// Round 15: attn + GEMM2 fused — one block per window, 12 waves (768 thr),
// 1 head/wave (R2's serialization eliminated), O^T -> 50KB LDS via R14's
// 4-lane transpose, ONE barrier, then the same waves run GEMM2 (wave w ->
// 32 cols; A from LDS, WmT from L2). Kills the 200MB attnout round-trip +
// one dispatch gap. prep_all/gemm1 frozen (R13/R12).

typedef __attribute__((ext_vector_type(4))) float f32x4;
typedef __attribute__((ext_vector_type(4))) short s16x4;
typedef __attribute__((ext_vector_type(8))) short s16x8;

#define DEVI static __device__ __forceinline__

DEVI unsigned short f2bf(float f) {
  union { float f; uint32_t u; } v; v.f = f;
  return (unsigned short)((v.u + 0x7FFFu + ((v.u >> 16) & 1u)) >> 16);
}

DEVI uint32_t pk2(float lo, float hi) {
  return (uint32_t)f2bf(lo) | ((uint32_t)f2bf(hi) << 16);
}

DEVI f32x4 zero4() { f32x4 z; z[0] = 0.f; z[1] = 0.f; z[2] = 0.f; z[3] = 0.f; return z; }

#if defined(__has_builtin)
#if __has_builtin(__builtin_amdgcn_mfma_f32_16x16x16bf16_1k)
#define MFMA16_BUILTIN 1
#endif
#if __has_builtin(__builtin_amdgcn_global_load_lds)
#define HAS_GLLDS 1
#endif
#endif

DEVI f32x4 mfma16(s16x4 a, s16x4 b, f32x4 c) {
#ifdef MFMA16_BUILTIN
  return __builtin_amdgcn_mfma_f32_16x16x16bf16_1k(a, b, c, 0, 0, 0);
#else
  asm volatile("v_mfma_f32_16x16x16_bf16 %0, %1, %2, %0" : "+v"(c) : "v"(a), "v"(b));
  return c;
#endif
}

DEVI f32x4 mfma32(s16x8 a, s16x8 b, f32x4 c) {
  return __builtin_amdgcn_mfma_f32_16x16x32_bf16(a, b, c, 0, 0, 0);
}

DEVI void stage1k(const unsigned short* g_lane, unsigned short* lds_base) {
#ifdef HAS_GLLDS
  __builtin_amdgcn_global_load_lds(
      (const __attribute__((address_space(1))) unsigned int*)g_lane,
      (__attribute__((address_space(3))) unsigned int*)lds_base, 16, 0, 0);
#else
  *(s16x8*)(lds_base + (threadIdx.x & 63) * 8) = *(const s16x8*)g_lane;
#endif
}

__global__ void fill_val(float* o, int n, float v) {
  int t = blockIdx.x * 256 + threadIdx.x;
  if (t < n) o[t] = v;
}

// ---------------- merged prep (R13 verbatim) ----------------
__global__ __launch_bounds__(256) void prep_all(
    const float* __restrict__ x, unsigned short* __restrict__ xb,
    const float* __restrict__ Wqkv, unsigned short* __restrict__ WqkvT,
    const float* __restrict__ Wm, unsigned short* __restrict__ WmT,
    const float* __restrict__ bqkv, float* __restrict__ bqkvs,
    const float* __restrict__ rel, float* __restrict__ biasF) {
  const int b = blockIdx.x;
  if (b < 2048) {
    const size_t nchunk = 131072UL * 384 / 8;
    for (size_t i = (size_t)b * 256 + threadIdx.x; i < nchunk; i += 2048UL * 256) {
      f32x4 a = *(const f32x4*)(x + i * 8);
      f32x4 c = *(const f32x4*)(x + i * 8 + 4);
      s16x8 p;
      p[0] = (short)f2bf(a[0]); p[1] = (short)f2bf(a[1]);
      p[2] = (short)f2bf(a[2]); p[3] = (short)f2bf(a[3]);
      p[4] = (short)f2bf(c[0]); p[5] = (short)f2bf(c[1]);
      p[6] = (short)f2bf(c[2]); p[7] = (short)f2bf(c[3]);
      *(s16x8*)(xb + i * 8) = p;
    }
  } else if (b == 2048) {
    for (int t = threadIdx.x; t < 1152; t += 256)
      bqkvs[t] = bqkv[t] * ((t < 384) ? 0.17677669529663687f : 1.0f);
  } else if (b < 2097) {
    int t = (b - 2049) * 256 + threadIdx.x;  // 12288
    if (t < 12288) {
      int h = t >> 10;
      int r = (t >> 6) & 15;
      int lane = t & 63;
      int jt = r >> 2, it = r & 3;
      int lg = lane >> 4, lr = lane & 15;
      int i = it * 16 + lr;
#pragma unroll
      for (int e = 0; e < 4; ++e) {
        int j = jt * 16 + lg * 4 + e;
        int idx = ((i >> 3) - (j >> 3) + 7) * 15 + ((i & 7) - (j & 7) + 7);
        biasF[t * 4 + e] = rel[idx * 12 + h];
      }
    }
  } else if (b < 2673) {
    int t = (b - 2097) * 256 + threadIdx.x;  // 147456
    int n = t / 384, k = t - n * 384;
    WmT[t] = f2bf(Wm[(size_t)k * 384 + n]);
  } else {
    int t = (b - 2673) * 256 + threadIdx.x;  // 442368
    int n = t / 384, k = t - n * 384;
    float s = (n < 384) ? 0.17677669529663687f : 1.0f;
    WqkvT[t] = f2bf(Wqkv[(size_t)k * 1152 + n] * s);
  }
}

// ---------------- GEMM1 (R12 verbatim, counted-vmcnt dbuf + T2 swizzle) ----------
template <bool QKV_EPI>
__global__ __launch_bounds__(512, 4) void gemm_k(const unsigned short* __restrict__ A,
                                                 const unsigned short* __restrict__ BT,
                                                 const float* __restrict__ bias,
                                                 void* __restrict__ Cv) {
  constexpr int K = 384;
  constexpr int NT = QKV_EPI ? 9 : 3;
  constexpr int N = NT * 128;
  __shared__ unsigned short sm[2][16384];
  const int bid = blockIdx.x;
  const int swz = (bid & 7) * (NT * 128) + (bid >> 3);
  const int n0 = (swz % NT) * 128;
  const int m0 = (swz / NT) * 128;
  const int tid = threadIdx.x;
  const int lane = tid & 63, wv = tid >> 6;
  const int wr = wv >> 2, wc = wv & 3;
  const int lg = lane >> 4, lr = lane & 15;

  const int scol = ((lane & 7) ^ (lane >> 3)) * 8;
  const unsigned short* Ag = A + (size_t)(m0 + wv * 16 + (lane >> 3)) * K + scol;
  const unsigned short* Bg = BT + (size_t)(n0 + wv * 16 + (lane >> 3)) * K + scol;

  f32x4 acc[4][2];
#pragma unroll
  for (int i = 0; i < 4; ++i)
#pragma unroll
    for (int j = 0; j < 2; ++j) acc[i][j] = zero4();

  auto STAGE = [&](int buf, int k0) {
#pragma unroll
    for (int c2 = 0; c2 < 2; ++c2)
      stage1k(Ag + (size_t)(c2 * 8) * K + k0, &sm[buf][(wv * 16 + c2 * 8) * 64]);
#pragma unroll
    for (int c2 = 0; c2 < 2; ++c2)
      stage1k(Bg + (size_t)(c2 * 8) * K + k0, &sm[buf][8192 + (wv * 16 + c2 * 8) * 64]);
  };
  const int sa = (lr & 7) << 3;
  auto COMPUTE = [&](int buf) {
#pragma unroll
    for (int kk = 0; kk < 64; kk += 32) {
      s16x8 af[4], bf[2];
#pragma unroll
      for (int mt = 0; mt < 4; ++mt)
        af[mt] = *(const s16x8*)&sm[buf][(wr * 64 + 16 * mt + lr) * 64 + ((kk + 8 * lg) ^ sa)];
#pragma unroll
      for (int nt = 0; nt < 2; ++nt)
        bf[nt] = *(const s16x8*)&sm[buf][8192 + (wc * 32 + 16 * nt + lr) * 64 + ((kk + 8 * lg) ^ sa)];
#pragma unroll
      for (int mt = 0; mt < 4; ++mt)
#pragma unroll
        for (int nt = 0; nt < 2; ++nt)
          acc[mt][nt] = mfma32(af[mt], bf[nt], acc[mt][nt]);
    }
  };

  STAGE(0, 0);
  int cur = 0;
#pragma unroll 1
  for (int t = 0; t < 5; ++t) {
    STAGE(cur ^ 1, (t + 1) * 64);
    asm volatile("s_waitcnt vmcnt(4)" ::: "memory");
    __builtin_amdgcn_sched_barrier(0);
    __builtin_amdgcn_s_barrier();
    __builtin_amdgcn_sched_barrier(0);
    COMPUTE(cur);
    __builtin_amdgcn_sched_barrier(0);
    __builtin_amdgcn_s_barrier();
    cur ^= 1;
  }
  asm volatile("s_waitcnt vmcnt(0)" ::: "memory");
  __builtin_amdgcn_sched_barrier(0);
  __builtin_amdgcn_s_barrier();
  __builtin_amdgcn_sched_barrier(0);
  COMPUTE(cur);

  const int crow = m0 + wr * 64 + 4 * lg;
  const int ccol = n0 + wc * 32 + lr;
  if constexpr (QKV_EPI) {
    const int sel = n0 / 384;
    unsigned short* qkv = (unsigned short*)Cv;
    if (sel < 2) {
      unsigned short* tile = &sm[0][0];
#pragma unroll
      for (int nt = 0; nt < 2; ++nt) {
        const int cc = wc * 32 + 16 * nt + lr;
        const float bv = bias[n0 + cc];
#pragma unroll
        for (int mt = 0; mt < 4; ++mt) {
#pragma unroll
          for (int e = 0; e < 4; ++e) {
            const int r = wr * 64 + 16 * mt + 4 * lg + e;
            tile[r * 128 + (cc ^ ((r & 7) << 3))] = f2bf(acc[mt][nt][e] + bv);
          }
        }
      }
      __syncthreads();
      const int hbase = (n0 - sel * 384) >> 5;
      const int tr = wv * 16 + (lane >> 2);
      const int gtok = m0 + tr;
      const int w2 = gtok >> 6, t0r = gtok & 63;
#pragma unroll
      for (int hh = 0; hh < 4; ++hh) {
        const int chunk = hh * 4 + (lane & 3);
        s16x8 v = *(const s16x8*)&tile[tr * 128 + ((chunk * 8) ^ ((tr & 7) << 3))];
        unsigned short* dst = qkv + (((size_t)w2 * 12 + hbase + hh) * 3 + sel) * 2048 +
                              t0r * 32 + (lane & 3) * 8;
        *(s16x8*)dst = v;
      }
    } else {
      const int window = crow >> 6;
      const int t0 = crow & 63;
#pragma unroll
      for (int nt = 0; nt < 2; ++nt) {
        const int col = ccol + 16 * nt;
        const int hcol = col - 768;
        const int h = hcol >> 5, d = hcol & 31;
        const float bv = bias[col];
        unsigned short* base = qkv + (((size_t)window * 12 + h) * 3 + 2) * 2048;
#pragma unroll
        for (int mt = 0; mt < 4; ++mt) {
          s16x4 pk;
#pragma unroll
          for (int e = 0; e < 4; ++e) pk[e] = (short)f2bf(acc[mt][nt][e] + bv);
          *(s16x4*)&base[d * 64 + t0 + 16 * mt] = pk;
        }
      }
    }
  } else {
    float* C = (float*)Cv;
#pragma unroll
    for (int mt = 0; mt < 4; ++mt)
#pragma unroll
      for (int nt = 0; nt < 2; ++nt) {
        const int col = ccol + 16 * nt;
        const float bv = bias[col];
#pragma unroll
        for (int e = 0; e < 4; ++e)
          C[(size_t)(crow + 16 * mt + e) * N + col] = acc[mt][nt][e] + bv;
      }
  }
}

// ---------------- fused attention + GEMM2: one block per window, 12 waves ----------
// Phase 1 (wave wv = head wv): R14 attn body; O^T 4-lane-transposed into
// att_s[64][392] (16B stores, 2-way bank pattern). One barrier.
// Phase 2: out[64,384] = att_s @ Wm + bm; wave wv -> cols [wv*32, +32),
// A-frags from LDS, B-frags from WmT (L2-resident, 288KB).
__global__ __launch_bounds__(768) void attn_gemm2_k(const unsigned short* __restrict__ qkv,
                                                    const float* __restrict__ biasF,
                                                    const unsigned short* __restrict__ WmT,
                                                    const float* __restrict__ bm,
                                                    float* __restrict__ out) {
  __shared__ unsigned short att_s[64 * 392];  // 50176 B
  const int lane = threadIdx.x & 63;
  const int wv = threadIdx.x >> 6;  // 0..11 = head
  const int window = blockIdx.x;    // [0, 2048)
  const int h = wv;
  const int lg = lane >> 4, lr = lane & 15;

  const unsigned short* hb = qkv + ((size_t)window * 12 + h) * 6144;
  const unsigned short* Qh = hb;
  const unsigned short* Kh = hb + 2048;
  const unsigned short* Vth = hb + 4096;

  s16x8 ka[4], qb[4];
#pragma unroll
  for (int jt = 0; jt < 4; ++jt)
    ka[jt] = *(const s16x8*)&Kh[(jt * 16 + lr) * 32 + 8 * lg];
#pragma unroll
  for (int it = 0; it < 4; ++it)
    qb[it] = *(const s16x8*)&Qh[(it * 16 + lr) * 32 + 8 * lg];

  f32x4 c[4][4];
#pragma unroll
  for (int a = 0; a < 4; ++a)
#pragma unroll
    for (int b2 = 0; b2 < 4; ++b2) c[a][b2] = zero4();

#pragma unroll
  for (int jt = 0; jt < 4; ++jt)
#pragma unroll
    for (int it = 0; it < 4; ++it)
      c[jt][it] = mfma32(ka[jt], qb[it], c[jt][it]);

  const f32x4* bF = (const f32x4*)biasF + ((size_t)h * 16) * 64 + lane;
#pragma unroll
  for (int jt = 0; jt < 4; ++jt)
#pragma unroll
    for (int it = 0; it < 4; ++it)
      c[jt][it] += bF[(jt * 4 + it) * 64];

  s16x4 pb[4][4];
#pragma unroll
  for (int it = 0; it < 4; ++it) {
    float m = -3.0e38f;
#pragma unroll
    for (int jt = 0; jt < 4; ++jt)
#pragma unroll
      for (int e = 0; e < 4; ++e) m = fmaxf(m, c[jt][it][e]);
    m = fmaxf(m, __shfl_xor(m, 16));
    m = fmaxf(m, __shfl_xor(m, 32));
    float s = 0.f;
#pragma unroll
    for (int jt = 0; jt < 4; ++jt)
#pragma unroll
      for (int e = 0; e < 4; ++e) {
        float p = __expf(c[jt][it][e] - m);
        c[jt][it][e] = p;
        s += p;
      }
    s += __shfl_xor(s, 16);
    s += __shfl_xor(s, 32);
    const float inv = 1.f / s;
#pragma unroll
    for (int jt = 0; jt < 4; ++jt) {
      s16x4 pk;
#pragma unroll
      for (int e = 0; e < 4; ++e) pk[e] = (short)f2bf(c[jt][it][e] * inv);
      pb[jt][it] = pk;
    }
  }

  f32x4 o[2][4];
#pragma unroll
  for (int a = 0; a < 2; ++a)
#pragma unroll
    for (int b2 = 0; b2 < 4; ++b2) o[a][b2] = zero4();

#pragma unroll
  for (int jt = 0; jt < 4; ++jt) {
    s16x4 va[2];
#pragma unroll
    for (int dt = 0; dt < 2; ++dt)
      va[dt] = *(const s16x4*)&Vth[(dt * 16 + lr) * 64 + jt * 16 + 4 * lg];
#pragma unroll
    for (int dt = 0; dt < 2; ++dt)
#pragma unroll
      for (int it = 0; it < 4; ++it)
        o[dt][it] = mfma16(va[dt], pb[jt][it], o[dt][it]);
  }

  // R14 4-lane transpose -> LDS: lane lg holds d[8lg,8lg+8) of token it*16+lr.
#pragma unroll
  for (int it = 0; it < 4; ++it) {
    const uint32_t p0 = pk2(o[0][it][0], o[0][it][1]);
    const uint32_t p1 = pk2(o[0][it][2], o[0][it][3]);
    const uint32_t q0 = pk2(o[1][it][0], o[1][it][1]);
    const uint32_t q1 = pk2(o[1][it][2], o[1][it][3]);

    const uint32_t x16_0 = __shfl_xor((int)(lg == 2 ? q0 : p0), 16);
    const uint32_t x16_1 = __shfl_xor((int)(lg == 2 ? q1 : p1), 16);
    const uint32_t x32_0 = __shfl_xor((int)(lg == 0 ? q0 : p0), 32);
    const uint32_t x32_1 = __shfl_xor((int)(lg == 0 ? q1 : p1), 32);
    const uint32_t x48_0 = __shfl_xor((int)(lg == 1 ? q0 : p0), 48);
    const uint32_t x48_1 = __shfl_xor((int)(lg == 1 ? q1 : p1), 48);

    uint32_t w[4];
    w[0] = lg == 0 ? p0 : lg == 1 ? x48_0 : lg == 2 ? x32_0 : x16_0;
    w[1] = lg == 0 ? p1 : lg == 1 ? x48_1 : lg == 2 ? x32_1 : x16_1;
    w[2] = lg == 0 ? x16_0 : lg == 1 ? x32_0 : lg == 2 ? x48_0 : q0;
    w[3] = lg == 0 ? x16_1 : lg == 1 ? x32_1 : lg == 2 ? x48_1 : q1;

    *(uint4*)&att_s[(size_t)(it * 16 + lr) * 392 + h * 32 + 8 * lg] =
        make_uint4(w[0], w[1], w[2], w[3]);
  }

  __syncthreads();

  // ---- phase 2: GEMM2. wave wv -> output cols [wv*32, wv*32+32)
  f32x4 acc[4][2];
#pragma unroll
  for (int mt = 0; mt < 4; ++mt)
#pragma unroll
    for (int nt = 0; nt < 2; ++nt) acc[mt][nt] = zero4();

  const int n0w = wv * 32;
#pragma unroll 2
  for (int ks = 0; ks < 12; ++ks) {
    s16x8 af[4], bf[2];
#pragma unroll
    for (int mt = 0; mt < 4; ++mt)
      af[mt] = *(const s16x8*)&att_s[(16 * mt + lr) * 392 + ks * 32 + 8 * lg];
#pragma unroll
    for (int nt = 0; nt < 2; ++nt)
      bf[nt] = *(const s16x8*)&WmT[(size_t)(n0w + 16 * nt + lr) * 384 + ks * 32 + 8 * lg];
#pragma unroll
    for (int mt = 0; mt < 4; ++mt)
#pragma unroll
      for (int nt = 0; nt < 2; ++nt)
        acc[mt][nt] = mfma32(af[mt], bf[nt], acc[mt][nt]);
  }

  float* ob = out + (size_t)window * 64 * 384;
#pragma unroll
  for (int mt = 0; mt < 4; ++mt)
#pragma unroll
    for (int nt = 0; nt < 2; ++nt) {
      const int col = n0w + 16 * nt + lr;
      const float bv = bm[col];
#pragma unroll
      for (int e = 0; e < 4; ++e)
        ob[(size_t)(16 * mt + 4 * lg + e) * 384 + col] = acc[mt][nt][e] + bv;
    }
}

extern "C" void kernel_launch(void* const* d_in, const int* in_sizes, int n_in,
                              void* d_out, int out_size, void* d_ws, size_t ws_size,
                              hipStream_t stream) {
  const float* x = (const float*)d_in[0];
  const float* Wqkv = (const float*)d_in[1];
  const float* bqkv = (const float*)d_in[2];
  const float* Wm = (const float*)d_in[3];
  const float* bm = (const float*)d_in[4];
  const float* rel = (const float*)d_in[5];

  const size_t M = 131072;  // B*G*P
  char* ws = (char*)d_ws;
  size_t off = 0;
  unsigned short* qkv = (unsigned short*)(ws + off);   off += M * 1152 * 2;  // 302 MB
  unsigned short* xb = (unsigned short*)(ws + off);    off += M * 384 * 2;   // 100 MB
  unsigned short* WqkvT = (unsigned short*)(ws + off); off += 1152 * 384 * 2;
  unsigned short* WmT = (unsigned short*)(ws + off);   off += 384 * 384 * 2;
  float* biasF = (float*)(ws + off);                   off += 12 * 16 * 64 * 4 * 4;
  float* bqkvs = (float*)(ws + off);                   off += 1152 * 4;

  if (ws_size < off) {
    fill_val<<<(out_size + 255) / 256, 256, 0, stream>>>((float*)d_out, out_size, 12345.0f);
    return;
  }

  prep_all<<<4401, 256, 0, stream>>>(x, xb, Wqkv, WqkvT, Wm, WmT, bqkv, bqkvs, rel, biasF);
  gemm_k<true><<<9216, 512, 0, stream>>>(xb, WqkvT, bqkvs, qkv);
  attn_gemm2_k<<<2048, 768, 0, stream>>>(qkv, biasF, WmT, bm, (float*)d_out);
}